// Round 4
// baseline (880.799 us; speedup 1.0000x reference)
//
#include <hip/hip_runtime.h>

#define BB 32
#define NN 2048
#define MM 512
#define DD 512

typedef _Float16 half8f __attribute__((ext_vector_type(8)));
typedef float    f32x16 __attribute__((ext_vector_type(16)));

#define MFMA __builtin_amdgcn_mfma_f32_32x32x16_f16

// Packed fragment layout for a row-major [R][K] matrix (per-b slice), R%128==0, K%16==0.
// Fragment (32 rows x 16 k): lane l holds row r32*32+(l&31), halves kc*16+(l>>5)*8 .. +8,
// stored at panel*128K + kc*2048 + r32*512 + l*8 -> one fully-coalesced 1KB wave load.
__device__ __forceinline__ int pidx(int r, int k, int K) {
    return (r >> 7) * (K << 7) + ((k >> 4) << 11) + (((r >> 5) & 3) << 9)
         + (((r & 31) + (((k >> 3) & 1) << 5)) << 3) + (k & 7);
}
__device__ __forceinline__ int kpart(int k) {   // k-dependent part of pidx (r-panel folded by caller)
    return ((k >> 4) << 11) + (((k >> 3) & 1) << 8) + (k & 7);
}

// prepC: reads C once; emits (a) c1 partial dots (C·w1, atomics), (b) PCh/PCl packed fp16
// split of C*w3 ([n][k=d]), (c) PCt packed fp16 transpose ([d][k=n]) via LDS.
__global__ __launch_bounds__(256) void k_prepC(const float* __restrict__ C, const float* __restrict__ w,
                                               float* __restrict__ c1, _Float16* __restrict__ PCt,
                                               _Float16* __restrict__ PCh, _Float16* __restrict__ PCl) {
    __shared__ float Ls[64][65];               // [d][n] fp32 staging for the transpose
    const int bid = blockIdx.x;                // BB * 32 * 8
    const int b   = bid >> 8;
    const int nn0 = ((bid >> 3) & 31) << 6;
    const int dd0 = (bid & 7) << 6;
    const int tid = threadIdx.x;
    const int nl  = tid >> 2;                  // 0..63
    const int dl  = (tid & 3) << 4;            // 0,16,32,48
    const float* w1 = w;
    const float* w3 = w + 2 * DD;
    const size_t crow = ((size_t)(b * NN + nn0 + nl)) * DD + dd0 + dl;
    float4 v[4], u[4], t[4];
#pragma unroll
    for (int p = 0; p < 4; ++p) {
        v[p] = *(const float4*)(C + crow + p * 4);
        u[p] = *(const float4*)(w1 + dd0 + dl + p * 4);
        t[p] = *(const float4*)(w3 + dd0 + dl + p * 4);
    }
    float s = 0.f;
#pragma unroll
    for (int p = 0; p < 4; ++p) s += v[p].x * u[p].x + v[p].y * u[p].y + v[p].z * u[p].z + v[p].w * u[p].w;
    s += __shfl_xor(s, 1); s += __shfl_xor(s, 2);
    if ((tid & 3) == 0) atomicAdd(&c1[b * NN + nn0 + nl], s);
#pragma unroll
    for (int p = 0; p < 4; ++p) {
        Ls[dl + p * 4 + 0][nl] = v[p].x; Ls[dl + p * 4 + 1][nl] = v[p].y;
        Ls[dl + p * 4 + 2][nl] = v[p].z; Ls[dl + p * 4 + 3][nl] = v[p].w;
    }
    const size_t pb = (size_t)b * NN * DD;
#pragma unroll
    for (int q = 0; q < 2; ++q) {              // two 8-wide chunks
        float x[8];
#pragma unroll
        for (int e = 0; e < 8; ++e) {
            const int p = q * 2 + (e >> 2);
            const float* vp = &v[p].x; const float* tp = &t[p].x;
            x[e] = vp[e & 3] * tp[e & 3];
        }
        half8f hh, ll;
#pragma unroll
        for (int e = 0; e < 8; ++e) {
            _Float16 h = (_Float16)x[e]; hh[e] = h;
            ll[e] = (_Float16)((x[e] - (float)h) * 2048.f);
        }
        const int pi = pidx(nn0 + nl, dd0 + dl + q * 8, DD);
        *(half8f*)&PCh[pb + pi] = hh;
        *(half8f*)&PCl[pb + pi] = ll;
    }
    __syncthreads();
    const int d2 = tid >> 2, n2 = (tid & 3) << 4;
    const size_t tb = (size_t)b * DD * NN;
#pragma unroll
    for (int q = 0; q < 2; ++q) {
        const int nc = n2 + q * 8;
        half8f o;
#pragma unroll
        for (int j = 0; j < 8; ++j) o[j] = (_Float16)Ls[d2][nc + j];
        *(half8f*)&PCt[tb + pidx(dd0 + d2, nn0 + nc, NN)] = o;
    }
}

// prepQ: reads Q once; emits q2 partials (Q·w2), PQh/PQl packed split ([m][k=d]),
// PQt packed masked transpose ([d][k=m]).
__global__ __launch_bounds__(256) void k_prepQ(const float* __restrict__ Q, const int* __restrict__ Qmask,
                                               const float* __restrict__ w, float* __restrict__ q2,
                                               _Float16* __restrict__ PQt,
                                               _Float16* __restrict__ PQh, _Float16* __restrict__ PQl) {
    __shared__ float Ls[64][65];               // [d][m], Qmask-zeroed
    const int bid = blockIdx.x;                // BB * 8 * 8
    const int b   = bid >> 6;
    const int rem = bid & 63;
    const int mm0 = (rem >> 3) << 6;
    const int dd0 = (rem & 7) << 6;
    const int tid = threadIdx.x;
    const int ml  = tid >> 2;
    const int dl  = (tid & 3) << 4;
    const float* w2 = w + DD;
    const size_t qrow = ((size_t)(b * MM + mm0 + ml)) * DD + dd0 + dl;
    float4 v[4], u[4];
#pragma unroll
    for (int p = 0; p < 4; ++p) {
        v[p] = *(const float4*)(Q + qrow + p * 4);
        u[p] = *(const float4*)(w2 + dd0 + dl + p * 4);
    }
    float s = 0.f;
#pragma unroll
    for (int p = 0; p < 4; ++p) s += v[p].x * u[p].x + v[p].y * u[p].y + v[p].z * u[p].z + v[p].w * u[p].w;
    s += __shfl_xor(s, 1); s += __shfl_xor(s, 2);
    if ((tid & 3) == 0) atomicAdd(&q2[b * MM + mm0 + ml], s);
    const float z = Qmask[b * MM + mm0 + ml] ? 0.f : 1.f;
#pragma unroll
    for (int p = 0; p < 4; ++p) {
        Ls[dl + p * 4 + 0][ml] = v[p].x * z; Ls[dl + p * 4 + 1][ml] = v[p].y * z;
        Ls[dl + p * 4 + 2][ml] = v[p].z * z; Ls[dl + p * 4 + 3][ml] = v[p].w * z;
    }
    const size_t pb = (size_t)b * MM * DD;
#pragma unroll
    for (int q = 0; q < 2; ++q) {
        float x[8];
#pragma unroll
        for (int e = 0; e < 8; ++e) {
            const int p = q * 2 + (e >> 2);
            const float* vp = &v[p].x;
            x[e] = vp[e & 3];
        }
        half8f hh, ll;
#pragma unroll
        for (int e = 0; e < 8; ++e) {
            _Float16 h = (_Float16)x[e]; hh[e] = h;
            ll[e] = (_Float16)((x[e] - (float)h) * 2048.f);
        }
        const int pi = pidx(mm0 + ml, dd0 + dl + q * 8, DD);
        *(half8f*)&PQh[pb + pi] = hh;
        *(half8f*)&PQl[pb + pi] = ll;
    }
    __syncthreads();
    const int d2 = tid >> 2, m2 = (tid & 3) << 4;
    const size_t tb = (size_t)b * DD * MM;
#pragma unroll
    for (int q = 0; q < 2; ++q) {
        const int mc = m2 + q * 8;
        half8f o;
#pragma unroll
        for (int j = 0; j < 8; ++j) o[j] = (_Float16)Ls[d2][mc + j];
        *(half8f*)&PQt[tb + pidx(dd0 + d2, mm0 + mc, MM)] = o;
    }
}

// k_te: PEt[m][k=n] (packed) = Cmask-zeroed transpose of packed E[n][k=m].
__global__ __launch_bounds__(256) void k_te(const _Float16* __restrict__ PE, const int* __restrict__ Cmask,
                                            _Float16* __restrict__ PEt) {
    __shared__ float Ls[64][65];               // [m][n]
    const int bid = blockIdx.x;                // BB * 32 * 8
    const int b   = bid >> 8;
    const int nn0 = ((bid >> 3) & 31) << 6;
    const int mm0 = (bid & 7) << 6;
    const int tid = threadIdx.x;
    const int nl  = tid >> 2;
    const int ml  = (tid & 3) << 4;
    const float z = Cmask[b * NN + nn0 + nl] ? 0.f : 1.f;
    const size_t eb = (size_t)b * NN * MM;
#pragma unroll
    for (int q = 0; q < 2; ++q) {
        half8f v = *(const half8f*)&PE[eb + pidx(nn0 + nl, mm0 + ml + q * 8, MM)];
#pragma unroll
        for (int j = 0; j < 8; ++j) Ls[ml + q * 8 + j][nl] = (float)v[j] * z;
    }
    __syncthreads();
    const int m2 = tid >> 2, n2 = (tid & 3) << 4;
    const size_t tb = (size_t)b * MM * NN;
#pragma unroll
    for (int q = 0; q < 2; ++q) {
        const int nc = n2 + q * 8;
        half8f o;
#pragma unroll
        for (int j = 0; j < 8; ++j) o[j] = (_Float16)Ls[m2][nc + j];
        *(half8f*)&PEt[tb + pidx(mm0 + m2, nn0 + nc, NN)] = o;
    }
}

#define SG_LOAD(P, kc) { const int o_ = (kc) * 256;                                   \
    P##ah0 = pAh[o_]; P##ah1 = pAh[o_ + 64]; P##al0 = pAl[o_]; P##al1 = pAl[o_ + 64]; \
    P##bh0 = pBh[o_]; P##bh1 = pBh[o_ + 64]; P##bl0 = pBl[o_]; P##bl1 = pBl[o_ + 64]; }
#define SG_STEP(A0,A1,L0,L1,B0,B1,D0,D1)                                     \
    accH[0][0]=MFMA(A0,B0,accH[0][0],0,0,0); accH[0][1]=MFMA(A0,B1,accH[0][1],0,0,0); \
    accH[1][0]=MFMA(A1,B0,accH[1][0],0,0,0); accH[1][1]=MFMA(A1,B1,accH[1][1],0,0,0); \
    accX[0][0]=MFMA(A0,D0,accX[0][0],0,0,0); accX[0][0]=MFMA(L0,B0,accX[0][0],0,0,0); \
    accX[0][1]=MFMA(A0,D1,accX[0][1],0,0,0); accX[0][1]=MFMA(L0,B1,accX[0][1],0,0,0); \
    accX[1][0]=MFMA(A1,D0,accX[1][0],0,0,0); accX[1][0]=MFMA(L1,B0,accX[1][0],0,0,0); \
    accX[1][1]=MFMA(A1,D1,accX[1][1],0,0,0); accX[1][1]=MFMA(L1,B1,accX[1][1],0,0,0);

// k_sgemm: barrier-free K-loop. S = Ah·Bh + 2^-11(Ah·Bl + Al·Bh) from packed fragments;
// E (packed [n][k=m]) = fp16(exp(S + c1 + q2)); masked quantized row/col sums -> rsum/csum.
__global__ __launch_bounds__(256, 2) void k_sgemm(const _Float16* __restrict__ PCh, const _Float16* __restrict__ PCl,
                                                  const _Float16* __restrict__ PQh, const _Float16* __restrict__ PQl,
                                                  const int* __restrict__ Cmask, const int* __restrict__ Qmask,
                                                  const float* __restrict__ c1, const float* __restrict__ q2,
                                                  _Float16* __restrict__ E, float* __restrict__ rsum,
                                                  float* __restrict__ csum) {
    __shared__ float rowp[128], colp[128], cmz[128], qmz[128], c1s[128], q2s[128];
    const int hw  = blockIdx.x;
    const int bid = ((hw & 7) << 8) | (hw >> 3);   // XCD-chunked swizzle (2048 = 8*256)
    const int b   = bid >> 6;
    const int rem = bid & 63;
    const int n0  = (rem >> 2) << 7;
    const int m0  = (rem & 3) << 7;
    const int tid = threadIdx.x;
    const int lane = tid & 63;
    const int wid  = tid >> 6;
    const int wr = wid >> 1, wc = wid & 1;
    if (tid < 128) {
        rowp[tid] = 0.f; colp[tid] = 0.f;
        cmz[tid] = Cmask[b * NN + n0 + tid] ? 0.f : 1.f;
        c1s[tid] = c1[b * NN + n0 + tid];
    } else {
        const int t = tid - 128;
        qmz[t] = Qmask[b * MM + m0 + t] ? 0.f : 1.f;
        q2s[t] = q2[b * MM + m0 + t];
    }
    __syncthreads();
    const half8f* pAh = (const half8f*)(PCh + (size_t)b * NN * DD + (size_t)n0 * DD) + wr * 128 + lane;
    const half8f* pAl = (const half8f*)(PCl + (size_t)b * NN * DD + (size_t)n0 * DD) + wr * 128 + lane;
    const half8f* pBh = (const half8f*)(PQh + (size_t)b * MM * DD + (size_t)m0 * DD) + wc * 128 + lane;
    const half8f* pBl = (const half8f*)(PQl + (size_t)b * MM * DD + (size_t)m0 * DD) + wc * 128 + lane;
    f32x16 accH[2][2] = {};
    f32x16 accX[2][2] = {};
    half8f xah0, xah1, xal0, xal1, xbh0, xbh1, xbl0, xbl1;
    half8f yah0, yah1, yal0, yal1, ybh0, ybh1, ybl0, ybl1;
    SG_LOAD(x, 0);
    for (int kc = 0; kc < 32; kc += 2) {
        SG_LOAD(y, kc + 1);
        SG_STEP(xah0, xah1, xal0, xal1, xbh0, xbh1, xbl0, xbl1);
        if (kc + 2 < 32) SG_LOAD(x, kc + 2);
        SG_STEP(yah0, yah1, yal0, yal1, ybh0, ybh1, ybl0, ybl1);
    }
    // epilogue: C/D layout col=lane&31, row=(r&3)+8*(r>>2)+4*(lane>>5) [m74/m101-verified]
    const float inv2k = 4.8828125e-4f;  // 2^-11
    const int mcol0 = wc * 64 + (lane & 31);
    const float qz0 = qmz[mcol0], qz1 = qmz[mcol0 + 32];
    const float q2v0 = q2s[mcol0], q2v1 = q2s[mcol0 + 32];
    const int hi4 = (lane >> 5) << 2;
    const size_t ebase = (size_t)b * NN * MM + (size_t)n0 * MM;
    const int kp0 = kpart(m0 + mcol0);
    const int kp1 = kpart(m0 + mcol0 + 32);
    float colacc0 = 0.f, colacc1 = 0.f;
#pragma unroll
    for (int i = 0; i < 2; ++i) {
#pragma unroll
        for (int r = 0; r < 16; ++r) {
            const int nloc = wr * 64 + i * 32 + (r & 3) + ((r >> 2) << 3) + hi4;
            const float base = c1s[nloc];
            float S0 = accH[i][0][r] + accX[i][0][r] * inv2k + base + q2v0;
            float S1 = accH[i][1][r] + accX[i][1][r] * inv2k + base + q2v1;
            float e0 = __expf(S0), e1 = __expf(S1);
            _Float16 h0 = (_Float16)e0, h1 = (_Float16)e1;
            float eq0 = (float)h0, eq1 = (float)h1;
            const int rp = (((nloc >> 5) & 3) << 9) + ((nloc & 31) << 3);
            E[ebase + rp + kp0] = h0;
            E[ebase + rp + kp1] = h1;
            const float cz = cmz[nloc];
            colacc0 += eq0 * cz;
            colacc1 += eq1 * cz;
            float rv = eq0 * qz0 + eq1 * qz1;
            rv += __shfl_xor(rv, 1);  rv += __shfl_xor(rv, 2);
            rv += __shfl_xor(rv, 4);  rv += __shfl_xor(rv, 8);
            rv += __shfl_xor(rv, 16);
            if ((lane & 31) == 0) atomicAdd(&rowp[nloc], rv);
        }
    }
    atomicAdd(&colp[mcol0], colacc0);
    atomicAdd(&colp[mcol0 + 32], colacc1);
    __syncthreads();
    if (tid < 128) atomicAdd(&rsum[b * NN + n0 + tid], rowp[tid]);
    else atomicAdd(&csum[b * MM + m0 + tid - 128], colp[tid - 128]);
}

#define KT_LOAD(P, kc) { const int o_ = (kc) * 256;                     \
    P##a0 = pA[o_]; P##a1 = pA[o_ + 64]; P##b0 = pB[o_]; P##b1 = pB[o_ + 64]; }
#define KT_STEP(A0,A1,B0,B1)                                            \
    acc[0][0]=MFMA(A0,B0,acc[0][0],0,0,0); acc[0][1]=MFMA(A0,B1,acc[0][1],0,0,0); \
    acc[1][0]=MFMA(A1,B0,acc[1][0],0,0,0); acc[1][1]=MFMA(A1,B1,acc[1][1],0,0,0);

// k_T: barrier-free. Tt[d][k=m] (packed) = fp16((1/csum[m])·qz[m]·Σ_n Ct[d,n]·Et[m,n]).
__global__ __launch_bounds__(256, 2) void k_T(const _Float16* __restrict__ PCt,
                                              const _Float16* __restrict__ PEt,
                                              const float* __restrict__ csum,
                                              const int* __restrict__ Qmask,
                                              _Float16* __restrict__ Tt) {
    const int hw  = blockIdx.x;                    // 512
    const int bid = ((hw & 7) << 6) | (hw >> 3);   // bijective (512 = 8*64)
    const int b   = bid >> 4;
    const int rem = bid & 15;
    const int d0  = (rem >> 2) << 7;
    const int m0  = (rem & 3) << 7;
    const int tid = threadIdx.x;
    const int lane = tid & 63;
    const int wid  = tid >> 6;
    const int wr = wid >> 1, wc = wid & 1;
    const half8f* pA = (const half8f*)(PCt + (size_t)b * DD * NN + (size_t)d0 * NN) + wr * 128 + lane;
    const half8f* pB = (const half8f*)(PEt + (size_t)b * MM * NN + (size_t)m0 * NN) + wc * 128 + lane;
    f32x16 acc[2][2] = {};
    half8f xa0, xa1, xb0, xb1, ya0, ya1, yb0, yb1;
    KT_LOAD(x, 0);
    for (int kc = 0; kc < 128; kc += 2) {
        KT_LOAD(y, kc + 1);
        KT_STEP(xa0, xa1, xb0, xb1);
        if (kc + 2 < 128) KT_LOAD(x, kc + 2);
        KT_STEP(ya0, ya1, yb0, yb1);
    }
    const int mc0 = m0 + wc * 64 + (lane & 31);
    const float s0 = (Qmask[b * MM + mc0]      ? 0.f : 1.f) / csum[b * MM + mc0];
    const float s1 = (Qmask[b * MM + mc0 + 32] ? 0.f : 1.f) / csum[b * MM + mc0 + 32];
    const int hi4 = (lane >> 5) << 2;
    const size_t tbase = (size_t)b * DD * MM + (size_t)d0 * MM;
    const int kp0 = kpart(mc0);
    const int kp1 = kpart(mc0 + 32);
#pragma unroll
    for (int i = 0; i < 2; ++i) {
#pragma unroll
        for (int r = 0; r < 16; ++r) {
            const int dloc = wr * 64 + i * 32 + (r & 3) + ((r >> 2) << 3) + hi4;
            const int rp = (((dloc >> 5) & 3) << 9) + ((dloc & 31) << 3);
            Tt[tbase + rp + kp0] = (_Float16)(acc[i][0][r] * s0);
            Tt[tbase + rp + kp1] = (_Float16)(acc[i][1][r] * s1);
        }
    }
}

#define AB_LOAD(P, kc) { const int o_ = (kc) * 256;                     \
    P##e0 = pE[o_]; P##e1 = pE[o_ + 64]; P##q0 = pQ[o_]; P##q1 = pQ[o_ + 64]; \
    P##t0 = pT[o_]; P##t1 = pT[o_ + 64]; }
#define AB_STEP(E0,E1,Q0,Q1,T0,T1)                                      \
    accA[0][0]=MFMA(E0,Q0,accA[0][0],0,0,0); accA[0][1]=MFMA(E0,Q1,accA[0][1],0,0,0); \
    accA[1][0]=MFMA(E1,Q0,accA[1][0],0,0,0); accA[1][1]=MFMA(E1,Q1,accA[1][1],0,0,0); \
    accB[0][0]=MFMA(E0,T0,accB[0][0],0,0,0); accB[0][1]=MFMA(E0,T1,accB[0][1],0,0,0); \
    accB[1][0]=MFMA(E1,T0,accB[1][0],0,0,0); accB[1][1]=MFMA(E1,T1,accB[1][1],0,0,0);

// k_AB: barrier-free. A[n][d] = (1/rsum[n])·Σ_m E[n,m]·Qt[d,m]; Bout likewise with Tt.
__global__ __launch_bounds__(256, 2) void k_AB(const _Float16* __restrict__ E,
                                               const _Float16* __restrict__ PQt,
                                               const _Float16* __restrict__ Tt,
                                               const float* __restrict__ rsum,
                                               float* __restrict__ outA, float* __restrict__ outB) {
    const int hw  = blockIdx.x;
    const int bid = ((hw & 7) << 8) | (hw >> 3);
    const int b   = bid >> 6;
    const int rem = bid & 63;
    const int n0  = (rem >> 2) << 7;
    const int d0  = (rem & 3) << 7;
    const int tid = threadIdx.x;
    const int lane = tid & 63;
    const int wid  = tid >> 6;
    const int wr = wid >> 1, wc = wid & 1;
    const half8f* pE = (const half8f*)(E   + (size_t)b * NN * MM + (size_t)n0 * MM) + wr * 128 + lane;
    const half8f* pQ = (const half8f*)(PQt + (size_t)b * DD * MM + (size_t)d0 * MM) + wc * 128 + lane;
    const half8f* pT = (const half8f*)(Tt  + (size_t)b * DD * MM + (size_t)d0 * MM) + wc * 128 + lane;
    f32x16 accA[2][2] = {};
    f32x16 accB[2][2] = {};
    half8f xe0, xe1, xq0, xq1, xt0, xt1, ye0, ye1, yq0, yq1, yt0, yt1;
    AB_LOAD(x, 0);
    for (int kc = 0; kc < 32; kc += 2) {
        AB_LOAD(y, kc + 1);
        AB_STEP(xe0, xe1, xq0, xq1, xt0, xt1);
        if (kc + 2 < 32) AB_LOAD(x, kc + 2);
        AB_STEP(ye0, ye1, yq0, yq1, yt0, yt1);
    }
    const int dc = d0 + wc * 64 + (lane & 31);
#pragma unroll
    for (int i = 0; i < 2; ++i) {
#pragma unroll
        for (int r = 0; r < 16; ++r) {
            const int row = (r & 3) + ((r >> 2) << 3) + ((lane >> 5) << 2);
            const int n = n0 + wr * 64 + i * 32 + row;
            const float inv = __builtin_amdgcn_rcpf(rsum[b * NN + n]);
            const size_t o = ((size_t)(b * NN + n)) * DD + dc;
            outA[o]      = accA[i][0][r] * inv;
            outA[o + 32] = accA[i][1][r] * inv;
            outB[o]      = accB[i][0][r] * inv;
            outB[o + 32] = accB[i][1][r] * inv;
        }
    }
}

extern "C" void kernel_launch(void* const* d_in, const int* in_sizes, int n_in,
                              void* d_out, int out_size, void* d_ws, size_t ws_size,
                              hipStream_t stream) {
    const float* C = (const float*)d_in[0];
    const float* Q = (const float*)d_in[1];
    const int* Cmask = (const int*)d_in[2];
    const int* Qmask = (const int*)d_in[3];
    const float* w  = (const float*)d_in[4];

    const size_t BNM = (size_t)BB * NN * MM;   // 33.55M halves
    const size_t BMD = (size_t)BB * MM * DD;   // 8.39M halves
    const size_t BND = (size_t)BB * NN * DD;   // 33.55M halves
    const size_t BN  = (size_t)BB * NN;
    const size_t BM  = (size_t)BB * MM;

    // d_ws: E (packed), Tt (packed), PQt (packed) + fp32 vectors (~101 MB).
    _Float16* E   = (_Float16*)d_ws;
    _Float16* Tt  = E + BNM;
    _Float16* PQt = Tt + BMD;
    float* c1   = (float*)(PQt + BMD);
    float* q2   = c1 + BN;
    float* rsum = q2 + BM;
    float* csum = rsum + BN;

    // Scratch in d_out (268.4 MB): PCt|PCh|PCl|PQh|PQl = 67+67+67+16.8+16.8 = 234.9 MB.
    // PCh/PCl/PQh/PQl dead after k_sgemm; PEt reuses the PCh slot; PCt/PEt dead after k_T;
    // k_AB then overwrites d_out with outA/outB.
    _Float16* PCt = (_Float16*)d_out;
    _Float16* PCh = PCt + BND;
    _Float16* PCl = PCh + BND;
    _Float16* PQh = PCl + BND;
    _Float16* PQl = PQh + BMD;
    _Float16* PEt = PCh;   // reuse after k_sgemm

    hipMemsetAsync(c1, 0, 2 * (BN + BM) * sizeof(float), stream);  // c1,q2,rsum,csum contiguous

    k_prepQ<<<BB * 64, 256, 0, stream>>>(Q, Qmask, w, q2, PQt, PQh, PQl);
    k_prepC<<<BB * 256, 256, 0, stream>>>(C, w, c1, PCt, PCh, PCl);
    k_sgemm<<<2048, 256, 0, stream>>>(PCh, PCl, PQh, PQl, Cmask, Qmask, c1, q2, E, rsum, csum);
    k_te<<<BB * 256, 256, 0, stream>>>(E, Cmask, PEt);
    k_T<<<512, 256, 0, stream>>>(PCt, PEt, csum, Qmask, Tt);
    k_AB<<<2048, 256, 0, stream>>>(E, PQt, Tt, rsum,
                                   (float*)d_out, (float*)d_out + BND);
}

// Round 5
// 848.457 us; speedup vs baseline: 1.0381x; 1.0381x over previous
//
#include <hip/hip_runtime.h>

#define BB 32
#define NN 2048
#define MM 512
#define DD 512

typedef _Float16 half8f __attribute__((ext_vector_type(8)));
typedef float    f32x16 __attribute__((ext_vector_type(16)));

#define MFMA __builtin_amdgcn_mfma_f32_32x32x16_f16

// Packed fragment layout for a row-major [R][K] matrix (per-b slice), R%128==0, K%16==0.
// Fragment (32 rows x 16 k): lane l holds row r32*32+(l&31), halves kc*16+(l>>5)*8 .. +8,
// stored at panel*128K + kc*2048 + r32*512 + l*8 -> one fully-coalesced 1KB wave load.
__device__ __forceinline__ int pidx(int r, int k, int K) {
    return (r >> 7) * (K << 7) + ((k >> 4) << 11) + (((r >> 5) & 3) << 9)
         + (((r & 31) + (((k >> 3) & 1) << 5)) << 3) + (k & 7);
}
__device__ __forceinline__ int kpart(int k) {   // k-dependent part of pidx (r-panel folded by caller)
    return ((k >> 4) << 11) + (((k >> 3) & 1) << 8) + (k & 7);
}

// prepC: reads C once; emits (a) c1 partial dots (C·w1, atomics), (b) PCh/PCl packed fp16
// split of C*w3 ([n][k=d]), (c) PCt packed fp16 transpose ([d][k=n]) via LDS.
__global__ __launch_bounds__(256) void k_prepC(const float* __restrict__ C, const float* __restrict__ w,
                                               float* __restrict__ c1, _Float16* __restrict__ PCt,
                                               _Float16* __restrict__ PCh, _Float16* __restrict__ PCl) {
    __shared__ float Ls[64][65];               // [d][n] fp32 staging for the transpose
    const int bid = blockIdx.x;                // BB * 32 * 8
    const int b   = bid >> 8;
    const int nn0 = ((bid >> 3) & 31) << 6;
    const int dd0 = (bid & 7) << 6;
    const int tid = threadIdx.x;
    const int nl  = tid >> 2;                  // 0..63
    const int dl  = (tid & 3) << 4;            // 0,16,32,48
    const float* w1 = w;
    const float* w3 = w + 2 * DD;
    const size_t crow = ((size_t)(b * NN + nn0 + nl)) * DD + dd0 + dl;
    float4 v[4], u[4], t[4];
#pragma unroll
    for (int p = 0; p < 4; ++p) {
        v[p] = *(const float4*)(C + crow + p * 4);
        u[p] = *(const float4*)(w1 + dd0 + dl + p * 4);
        t[p] = *(const float4*)(w3 + dd0 + dl + p * 4);
    }
    float s = 0.f;
#pragma unroll
    for (int p = 0; p < 4; ++p) s += v[p].x * u[p].x + v[p].y * u[p].y + v[p].z * u[p].z + v[p].w * u[p].w;
    s += __shfl_xor(s, 1); s += __shfl_xor(s, 2);
    if ((tid & 3) == 0) atomicAdd(&c1[b * NN + nn0 + nl], s);
#pragma unroll
    for (int p = 0; p < 4; ++p) {
        Ls[dl + p * 4 + 0][nl] = v[p].x; Ls[dl + p * 4 + 1][nl] = v[p].y;
        Ls[dl + p * 4 + 2][nl] = v[p].z; Ls[dl + p * 4 + 3][nl] = v[p].w;
    }
    const size_t pb = (size_t)b * NN * DD;
#pragma unroll
    for (int q = 0; q < 2; ++q) {              // two 8-wide chunks
        float x[8];
#pragma unroll
        for (int e = 0; e < 8; ++e) {
            const int p = q * 2 + (e >> 2);
            const float* vp = &v[p].x; const float* tp = &t[p].x;
            x[e] = vp[e & 3] * tp[e & 3];
        }
        half8f hh, ll;
#pragma unroll
        for (int e = 0; e < 8; ++e) {
            _Float16 h = (_Float16)x[e]; hh[e] = h;
            ll[e] = (_Float16)((x[e] - (float)h) * 2048.f);
        }
        const int pi = pidx(nn0 + nl, dd0 + dl + q * 8, DD);
        *(half8f*)&PCh[pb + pi] = hh;
        *(half8f*)&PCl[pb + pi] = ll;
    }
    __syncthreads();
    const int d2 = tid >> 2, n2 = (tid & 3) << 4;
    const size_t tb = (size_t)b * DD * NN;
#pragma unroll
    for (int q = 0; q < 2; ++q) {
        const int nc = n2 + q * 8;
        half8f o;
#pragma unroll
        for (int j = 0; j < 8; ++j) o[j] = (_Float16)Ls[d2][nc + j];
        *(half8f*)&PCt[tb + pidx(dd0 + d2, nn0 + nc, NN)] = o;
    }
}

// prepQ: reads Q once; emits q2 partials (Q·w2), PQh/PQl packed split ([m][k=d]),
// PQt packed masked transpose ([d][k=m]).
__global__ __launch_bounds__(256) void k_prepQ(const float* __restrict__ Q, const int* __restrict__ Qmask,
                                               const float* __restrict__ w, float* __restrict__ q2,
                                               _Float16* __restrict__ PQt,
                                               _Float16* __restrict__ PQh, _Float16* __restrict__ PQl) {
    __shared__ float Ls[64][65];               // [d][m], Qmask-zeroed
    const int bid = blockIdx.x;                // BB * 8 * 8
    const int b   = bid >> 6;
    const int rem = bid & 63;
    const int mm0 = (rem >> 3) << 6;
    const int dd0 = (rem & 7) << 6;
    const int tid = threadIdx.x;
    const int ml  = tid >> 2;
    const int dl  = (tid & 3) << 4;
    const float* w2 = w + DD;
    const size_t qrow = ((size_t)(b * MM + mm0 + ml)) * DD + dd0 + dl;
    float4 v[4], u[4];
#pragma unroll
    for (int p = 0; p < 4; ++p) {
        v[p] = *(const float4*)(Q + qrow + p * 4);
        u[p] = *(const float4*)(w2 + dd0 + dl + p * 4);
    }
    float s = 0.f;
#pragma unroll
    for (int p = 0; p < 4; ++p) s += v[p].x * u[p].x + v[p].y * u[p].y + v[p].z * u[p].z + v[p].w * u[p].w;
    s += __shfl_xor(s, 1); s += __shfl_xor(s, 2);
    if ((tid & 3) == 0) atomicAdd(&q2[b * MM + mm0 + ml], s);
    const float z = Qmask[b * MM + mm0 + ml] ? 0.f : 1.f;
#pragma unroll
    for (int p = 0; p < 4; ++p) {
        Ls[dl + p * 4 + 0][ml] = v[p].x * z; Ls[dl + p * 4 + 1][ml] = v[p].y * z;
        Ls[dl + p * 4 + 2][ml] = v[p].z * z; Ls[dl + p * 4 + 3][ml] = v[p].w * z;
    }
    const size_t pb = (size_t)b * MM * DD;
#pragma unroll
    for (int q = 0; q < 2; ++q) {
        float x[8];
#pragma unroll
        for (int e = 0; e < 8; ++e) {
            const int p = q * 2 + (e >> 2);
            const float* vp = &v[p].x;
            x[e] = vp[e & 3];
        }
        half8f hh, ll;
#pragma unroll
        for (int e = 0; e < 8; ++e) {
            _Float16 h = (_Float16)x[e]; hh[e] = h;
            ll[e] = (_Float16)((x[e] - (float)h) * 2048.f);
        }
        const int pi = pidx(mm0 + ml, dd0 + dl + q * 8, DD);
        *(half8f*)&PQh[pb + pi] = hh;
        *(half8f*)&PQl[pb + pi] = ll;
    }
    __syncthreads();
    const int d2 = tid >> 2, m2 = (tid & 3) << 4;
    const size_t tb = (size_t)b * DD * MM;
#pragma unroll
    for (int q = 0; q < 2; ++q) {
        const int mc = m2 + q * 8;
        half8f o;
#pragma unroll
        for (int j = 0; j < 8; ++j) o[j] = (_Float16)Ls[d2][mc + j];
        *(half8f*)&PQt[tb + pidx(dd0 + d2, mm0 + mc, MM)] = o;
    }
}

// k_te: PEt[m][k=n] (packed) = Cmask-zeroed transpose of packed E[n][k=m].
__global__ __launch_bounds__(256) void k_te(const _Float16* __restrict__ PE, const int* __restrict__ Cmask,
                                            _Float16* __restrict__ PEt) {
    __shared__ float Ls[64][65];               // [m][n]
    const int bid = blockIdx.x;                // BB * 32 * 8
    const int b   = bid >> 8;
    const int nn0 = ((bid >> 3) & 31) << 6;
    const int mm0 = (bid & 7) << 6;
    const int tid = threadIdx.x;
    const int nl  = tid >> 2;
    const int ml  = (tid & 3) << 4;
    const float z = Cmask[b * NN + nn0 + nl] ? 0.f : 1.f;
    const size_t eb = (size_t)b * NN * MM;
#pragma unroll
    for (int q = 0; q < 2; ++q) {
        half8f v = *(const half8f*)&PE[eb + pidx(nn0 + nl, mm0 + ml + q * 8, MM)];
#pragma unroll
        for (int j = 0; j < 8; ++j) Ls[ml + q * 8 + j][nl] = (float)v[j] * z;
    }
    __syncthreads();
    const int m2 = tid >> 2, n2 = (tid & 3) << 4;
    const size_t tb = (size_t)b * MM * NN;
#pragma unroll
    for (int q = 0; q < 2; ++q) {
        const int nc = n2 + q * 8;
        half8f o;
#pragma unroll
        for (int j = 0; j < 8; ++j) o[j] = (_Float16)Ls[m2][nc + j];
        *(half8f*)&PEt[tb + pidx(mm0 + m2, nn0 + nc, NN)] = o;
    }
}

#define SG_LOAD(P, kc) { const int o_ = (kc) * 256;                                   \
    P##ah0 = pAh[o_]; P##ah1 = pAh[o_ + 64]; P##al0 = pAl[o_]; P##al1 = pAl[o_ + 64]; \
    P##bh0 = pBh[o_]; P##bh1 = pBh[o_ + 64]; P##bl0 = pBl[o_]; P##bl1 = pBl[o_ + 64]; }
#define SG_STEP(P)                                                                      \
    accH[0][0]=MFMA(P##ah0,P##bh0,accH[0][0],0,0,0); accH[0][1]=MFMA(P##ah0,P##bh1,accH[0][1],0,0,0); \
    accH[1][0]=MFMA(P##ah1,P##bh0,accH[1][0],0,0,0); accH[1][1]=MFMA(P##ah1,P##bh1,accH[1][1],0,0,0); \
    accX[0][0]=MFMA(P##ah0,P##bl0,accX[0][0],0,0,0); accX[0][0]=MFMA(P##al0,P##bh0,accX[0][0],0,0,0); \
    accX[0][1]=MFMA(P##ah0,P##bl1,accX[0][1],0,0,0); accX[0][1]=MFMA(P##al0,P##bh1,accX[0][1],0,0,0); \
    accX[1][0]=MFMA(P##ah1,P##bl0,accX[1][0],0,0,0); accX[1][0]=MFMA(P##al1,P##bh0,accX[1][0],0,0,0); \
    accX[1][1]=MFMA(P##ah1,P##bl1,accX[1][1],0,0,0); accX[1][1]=MFMA(P##al1,P##bh1,accX[1][1],0,0,0);

// k_sgemm: barrier-free K-loop, 3-stage register pipeline (each stage consumed 2 STEPs
// after issue -> ~2x12 MFMA latency cover). S = Ah·Bh + 2^-11(Ah·Bl + Al·Bh);
// E (packed [n][k=m]) = fp16(exp(S + c1 + q2)); masked quantized row/col sums -> rsum/csum.
__global__ __launch_bounds__(256, 2) void k_sgemm(const _Float16* __restrict__ PCh, const _Float16* __restrict__ PCl,
                                                  const _Float16* __restrict__ PQh, const _Float16* __restrict__ PQl,
                                                  const int* __restrict__ Cmask, const int* __restrict__ Qmask,
                                                  const float* __restrict__ c1, const float* __restrict__ q2,
                                                  _Float16* __restrict__ E, float* __restrict__ rsum,
                                                  float* __restrict__ csum) {
    __shared__ float rowp[128], colp[128], cmz[128], qmz[128], c1s[128], q2s[128];
    const int hw  = blockIdx.x;
    const int bid = ((hw & 7) << 8) | (hw >> 3);   // XCD-chunked swizzle (2048 = 8*256)
    const int b   = bid >> 6;
    const int rem = bid & 63;
    const int n0  = (rem >> 2) << 7;
    const int m0  = (rem & 3) << 7;
    const int tid = threadIdx.x;
    const int lane = tid & 63;
    const int wid  = tid >> 6;
    const int wr = wid >> 1, wc = wid & 1;
    if (tid < 128) {
        rowp[tid] = 0.f; colp[tid] = 0.f;
        cmz[tid] = Cmask[b * NN + n0 + tid] ? 0.f : 1.f;
        c1s[tid] = c1[b * NN + n0 + tid];
    } else {
        const int t = tid - 128;
        qmz[t] = Qmask[b * MM + m0 + t] ? 0.f : 1.f;
        q2s[t] = q2[b * MM + m0 + t];
    }
    __syncthreads();
    const half8f* pAh = (const half8f*)(PCh + (size_t)b * NN * DD + (size_t)n0 * DD) + wr * 128 + lane;
    const half8f* pAl = (const half8f*)(PCl + (size_t)b * NN * DD + (size_t)n0 * DD) + wr * 128 + lane;
    const half8f* pBh = (const half8f*)(PQh + (size_t)b * MM * DD + (size_t)m0 * DD) + wc * 128 + lane;
    const half8f* pBl = (const half8f*)(PQl + (size_t)b * MM * DD + (size_t)m0 * DD) + wc * 128 + lane;
    f32x16 accH[2][2] = {};
    f32x16 accX[2][2] = {};
    half8f xah0, xah1, xal0, xal1, xbh0, xbh1, xbl0, xbl1;
    half8f yah0, yah1, yal0, yal1, ybh0, ybh1, ybl0, ybl1;
    half8f zah0, zah1, zal0, zal1, zbh0, zbh1, zbl0, zbl1;
    SG_LOAD(x, 0);
    SG_LOAD(y, 1);
    for (int kc = 0; kc < 30; kc += 3) {
        SG_LOAD(z, kc + 2);
        SG_STEP(x);
        SG_LOAD(x, kc + 3);
        SG_STEP(y);
        SG_LOAD(y, kc + 4);
        SG_STEP(z);
    }
    SG_STEP(x);   // kc = 30
    SG_STEP(y);   // kc = 31
    // epilogue: C/D layout col=lane&31, row=(r&3)+8*(r>>2)+4*(lane>>5) [m74/m101-verified]
    const float inv2k = 4.8828125e-4f;  // 2^-11
    const int mcol0 = wc * 64 + (lane & 31);
    const float qz0 = qmz[mcol0], qz1 = qmz[mcol0 + 32];
    const float q2v0 = q2s[mcol0], q2v1 = q2s[mcol0 + 32];
    const int hi4 = (lane >> 5) << 2;
    const size_t ebase = (size_t)b * NN * MM + (size_t)n0 * MM;
    const int kp0 = kpart(m0 + mcol0);
    const int kp1 = kpart(m0 + mcol0 + 32);
    float colacc0 = 0.f, colacc1 = 0.f;
#pragma unroll
    for (int i = 0; i < 2; ++i) {
#pragma unroll
        for (int r = 0; r < 16; ++r) {
            const int nloc = wr * 64 + i * 32 + (r & 3) + ((r >> 2) << 3) + hi4;
            const float base = c1s[nloc];
            float S0 = accH[i][0][r] + accX[i][0][r] * inv2k + base + q2v0;
            float S1 = accH[i][1][r] + accX[i][1][r] * inv2k + base + q2v1;
            float e0 = __expf(S0), e1 = __expf(S1);
            _Float16 h0 = (_Float16)e0, h1 = (_Float16)e1;
            float eq0 = (float)h0, eq1 = (float)h1;
            const int rp = (((nloc >> 5) & 3) << 9) + ((nloc & 31) << 3);
            E[ebase + rp + kp0] = h0;
            E[ebase + rp + kp1] = h1;
            const float cz = cmz[nloc];
            colacc0 += eq0 * cz;
            colacc1 += eq1 * cz;
            float rv = eq0 * qz0 + eq1 * qz1;
            rv += __shfl_xor(rv, 1);  rv += __shfl_xor(rv, 2);
            rv += __shfl_xor(rv, 4);  rv += __shfl_xor(rv, 8);
            rv += __shfl_xor(rv, 16);
            if ((lane & 31) == 0) atomicAdd(&rowp[nloc], rv);
        }
    }
    atomicAdd(&colp[mcol0], colacc0);
    atomicAdd(&colp[mcol0 + 32], colacc1);
    __syncthreads();
    if (tid < 128) atomicAdd(&rsum[b * NN + n0 + tid], rowp[tid]);
    else atomicAdd(&csum[b * MM + m0 + tid - 128], colp[tid - 128]);
}

#define KT_LOAD(P, kc) { const int o_ = (kc) * 256;                     \
    P##a0 = pA[o_]; P##a1 = pA[o_ + 64]; P##b0 = pB[o_]; P##b1 = pB[o_ + 64]; }
#define KT_STEP(P)                                                      \
    acc[0][0]=MFMA(P##a0,P##b0,acc[0][0],0,0,0); acc[0][1]=MFMA(P##a0,P##b1,acc[0][1],0,0,0); \
    acc[1][0]=MFMA(P##a1,P##b0,acc[1][0],0,0,0); acc[1][1]=MFMA(P##a1,P##b1,acc[1][1],0,0,0);

// k_T: barrier-free, 4-stage lead-3 pipeline. Tt[d][k=m] (packed) =
// fp16((1/csum[m])·qz[m]·Σ_n Ct[d,n]·Et[m,n]).
__global__ __launch_bounds__(256, 2) void k_T(const _Float16* __restrict__ PCt,
                                              const _Float16* __restrict__ PEt,
                                              const float* __restrict__ csum,
                                              const int* __restrict__ Qmask,
                                              _Float16* __restrict__ Tt) {
    const int hw  = blockIdx.x;                    // 512
    const int bid = ((hw & 7) << 6) | (hw >> 3);   // bijective (512 = 8*64)
    const int b   = bid >> 4;
    const int rem = bid & 15;
    const int d0  = (rem >> 2) << 7;
    const int m0  = (rem & 3) << 7;
    const int tid = threadIdx.x;
    const int lane = tid & 63;
    const int wid  = tid >> 6;
    const int wr = wid >> 1, wc = wid & 1;
    const half8f* pA = (const half8f*)(PCt + (size_t)b * DD * NN + (size_t)d0 * NN) + wr * 128 + lane;
    const half8f* pB = (const half8f*)(PEt + (size_t)b * MM * NN + (size_t)m0 * NN) + wc * 128 + lane;
    f32x16 acc[2][2] = {};
    half8f xa0, xa1, xb0, xb1, ya0, ya1, yb0, yb1;
    half8f za0, za1, zb0, zb1, ua0, ua1, ub0, ub1;
    KT_LOAD(x, 0);
    KT_LOAD(y, 1);
    KT_LOAD(z, 2);
    for (int kc = 0; kc < 128; kc += 4) {
        KT_LOAD(u, kc + 3);
        KT_STEP(x);
        if (kc + 4 < 128) KT_LOAD(x, kc + 4);
        KT_STEP(y);
        if (kc + 5 < 128) KT_LOAD(y, kc + 5);
        KT_STEP(z);
        if (kc + 6 < 128) KT_LOAD(z, kc + 6);
        KT_STEP(u);
    }
    const int mc0 = m0 + wc * 64 + (lane & 31);
    const float s0 = (Qmask[b * MM + mc0]      ? 0.f : 1.f) / csum[b * MM + mc0];
    const float s1 = (Qmask[b * MM + mc0 + 32] ? 0.f : 1.f) / csum[b * MM + mc0 + 32];
    const int hi4 = (lane >> 5) << 2;
    const size_t tbase = (size_t)b * DD * MM + (size_t)d0 * MM;
    const int kp0 = kpart(mc0);
    const int kp1 = kpart(mc0 + 32);
#pragma unroll
    for (int i = 0; i < 2; ++i) {
#pragma unroll
        for (int r = 0; r < 16; ++r) {
            const int dloc = wr * 64 + i * 32 + (r & 3) + ((r >> 2) << 3) + hi4;
            const int rp = (((dloc >> 5) & 3) << 9) + ((dloc & 31) << 3);
            Tt[tbase + rp + kp0] = (_Float16)(acc[i][0][r] * s0);
            Tt[tbase + rp + kp1] = (_Float16)(acc[i][1][r] * s1);
        }
    }
}

#define AB_LOAD(P, kc) { const int o_ = (kc) * 256;                     \
    P##e0 = pE[o_]; P##e1 = pE[o_ + 64]; P##q0 = pQ[o_]; P##q1 = pQ[o_ + 64]; \
    P##t0 = pT[o_]; P##t1 = pT[o_ + 64]; }
#define AB_STEP(P)                                                      \
    accA[0][0]=MFMA(P##e0,P##q0,accA[0][0],0,0,0); accA[0][1]=MFMA(P##e0,P##q1,accA[0][1],0,0,0); \
    accA[1][0]=MFMA(P##e1,P##q0,accA[1][0],0,0,0); accA[1][1]=MFMA(P##e1,P##q1,accA[1][1],0,0,0); \
    accB[0][0]=MFMA(P##e0,P##t0,accB[0][0],0,0,0); accB[0][1]=MFMA(P##e0,P##t1,accB[0][1],0,0,0); \
    accB[1][0]=MFMA(P##e1,P##t0,accB[1][0],0,0,0); accB[1][1]=MFMA(P##e1,P##t1,accB[1][1],0,0,0);

// k_AB: barrier-free, 4-stage lead-3 pipeline (each stage consumed 3 STEPs = 24 MFMAs
// after issue, covering L2 latency). A[n][d] = (1/rsum[n])·Σ_m E[n,m]·Qt[d,m]; Bout with Tt.
__global__ __launch_bounds__(256, 2) void k_AB(const _Float16* __restrict__ E,
                                               const _Float16* __restrict__ PQt,
                                               const _Float16* __restrict__ Tt,
                                               const float* __restrict__ rsum,
                                               float* __restrict__ outA, float* __restrict__ outB) {
    const int hw  = blockIdx.x;
    const int bid = ((hw & 7) << 8) | (hw >> 3);
    const int b   = bid >> 6;
    const int rem = bid & 63;
    const int n0  = (rem >> 2) << 7;
    const int d0  = (rem & 3) << 7;
    const int tid = threadIdx.x;
    const int lane = tid & 63;
    const int wid  = tid >> 6;
    const int wr = wid >> 1, wc = wid & 1;
    const half8f* pE = (const half8f*)(E   + (size_t)b * NN * MM + (size_t)n0 * MM) + wr * 128 + lane;
    const half8f* pQ = (const half8f*)(PQt + (size_t)b * DD * MM + (size_t)d0 * MM) + wc * 128 + lane;
    const half8f* pT = (const half8f*)(Tt  + (size_t)b * DD * MM + (size_t)d0 * MM) + wc * 128 + lane;
    f32x16 accA[2][2] = {};
    f32x16 accB[2][2] = {};
    half8f xe0, xe1, xq0, xq1, xt0, xt1;
    half8f ye0, ye1, yq0, yq1, yt0, yt1;
    half8f ze0, ze1, zq0, zq1, zt0, zt1;
    half8f ue0, ue1, uq0, uq1, ut0, ut1;
    AB_LOAD(x, 0);
    AB_LOAD(y, 1);
    AB_LOAD(z, 2);
    for (int kc = 0; kc < 32; kc += 4) {
        AB_LOAD(u, kc + 3);
        AB_STEP(x);
        if (kc + 4 < 32) AB_LOAD(x, kc + 4);
        AB_STEP(y);
        if (kc + 5 < 32) AB_LOAD(y, kc + 5);
        AB_STEP(z);
        if (kc + 6 < 32) AB_LOAD(z, kc + 6);
        AB_STEP(u);
    }
    const int dc = d0 + wc * 64 + (lane & 31);
#pragma unroll
    for (int i = 0; i < 2; ++i) {
#pragma unroll
        for (int r = 0; r < 16; ++r) {
            const int row = (r & 3) + ((r >> 2) << 3) + ((lane >> 5) << 2);
            const int n = n0 + wr * 64 + i * 32 + row;
            const float inv = __builtin_amdgcn_rcpf(rsum[b * NN + n]);
            const size_t o = ((size_t)(b * NN + n)) * DD + dc;
            outA[o]      = accA[i][0][r] * inv;
            outA[o + 32] = accA[i][1][r] * inv;
            outB[o]      = accB[i][0][r] * inv;
            outB[o + 32] = accB[i][1][r] * inv;
        }
    }
}

extern "C" void kernel_launch(void* const* d_in, const int* in_sizes, int n_in,
                              void* d_out, int out_size, void* d_ws, size_t ws_size,
                              hipStream_t stream) {
    const float* C = (const float*)d_in[0];
    const float* Q = (const float*)d_in[1];
    const int* Cmask = (const int*)d_in[2];
    const int* Qmask = (const int*)d_in[3];
    const float* w  = (const float*)d_in[4];

    const size_t BNM = (size_t)BB * NN * MM;   // 33.55M halves
    const size_t BMD = (size_t)BB * MM * DD;   // 8.39M halves
    const size_t BND = (size_t)BB * NN * DD;   // 33.55M halves
    const size_t BN  = (size_t)BB * NN;
    const size_t BM  = (size_t)BB * MM;

    // d_ws: E (packed), Tt (packed), PQt (packed) + fp32 vectors (~101 MB).
    _Float16* E   = (_Float16*)d_ws;
    _Float16* Tt  = E + BNM;
    _Float16* PQt = Tt + BMD;
    float* c1   = (float*)(PQt + BMD);
    float* q2   = c1 + BN;
    float* rsum = q2 + BM;
    float* csum = rsum + BN;

    // Scratch in d_out (268.4 MB): PCt|PCh|PCl|PQh|PQl = 67+67+67+16.8+16.8 = 234.9 MB.
    // PCh/PCl/PQh/PQl dead after k_sgemm; PEt reuses the PCh slot; PCt/PEt dead after k_T;
    // k_AB then overwrites d_out with outA/outB.
    _Float16* PCt = (_Float16*)d_out;
    _Float16* PCh = PCt + BND;
    _Float16* PCl = PCh + BND;
    _Float16* PQh = PCl + BND;
    _Float16* PQl = PQh + BMD;
    _Float16* PEt = PCh;   // reuse after k_sgemm

    hipMemsetAsync(c1, 0, 2 * (BN + BM) * sizeof(float), stream);  // c1,q2,rsum,csum contiguous

    k_prepQ<<<BB * 64, 256, 0, stream>>>(Q, Qmask, w, q2, PQt, PQh, PQl);
    k_prepC<<<BB * 256, 256, 0, stream>>>(C, w, c1, PCt, PCh, PCl);
    k_sgemm<<<2048, 256, 0, stream>>>(PCh, PCl, PQh, PQl, Cmask, Qmask, c1, q2, E, rsum, csum);
    k_te<<<BB * 256, 256, 0, stream>>>(E, Cmask, PEt);
    k_T<<<512, 256, 0, stream>>>(PCt, PEt, csum, Qmask, Tt);
    k_AB<<<2048, 256, 0, stream>>>(E, PQt, Tt, rsum,
                                   (float*)d_out, (float*)d_out + BND);
}

// Round 6
// 727.496 us; speedup vs baseline: 1.2107x; 1.1663x over previous
//
#include <hip/hip_runtime.h>

#define BB 32
#define NN 2048
#define MM 512
#define DD 512

typedef _Float16 half8f __attribute__((ext_vector_type(8)));
typedef float    f32x16 __attribute__((ext_vector_type(16)));

#define MFMA __builtin_amdgcn_mfma_f32_32x32x16_f16

// Packed fragment layout for a row-major [R][K] matrix (per-b slice), R%128==0, K%16==0.
// Fragment (32 rows x 16 k): lane l holds row r32*32+(l&31), halves kc*16+(l>>5)*8 .. +8,
// stored at panel*128K + kc*2048 + r32*512 + l*8 -> one fully-coalesced 1KB wave load,
// and a global_load_lds-compatible blob (wave-uniform LDS base + lane*16).
__device__ __forceinline__ int pidx(int r, int k, int K) {
    return (r >> 7) * (K << 7) + ((k >> 4) << 11) + (((r >> 5) & 3) << 9)
         + (((r & 31) + (((k >> 3) & 1) << 5)) << 3) + (k & 7);
}
__device__ __forceinline__ int kpart(int k) {   // k-dependent part of pidx (r-panel folded by caller)
    return ((k >> 4) << 11) + (((k >> 3) & 1) << 8) + (k & 7);
}

// 16B async global->LDS (DMA, no VGPR roundtrip). LDS dest must be wave-uniform;
// HW adds lane*16. Global src is per-lane.
__device__ __forceinline__ void glds16(const void* g, void* l) {
    __builtin_amdgcn_global_load_lds(
        (const __attribute__((address_space(1))) unsigned int*)g,
        (__attribute__((address_space(3))) unsigned int*)l, 16, 0, 0);
}

// prepC: reads C once; emits (a) c1 partial dots (C·w1, atomics), (b) PCh/PCl packed fp16
// split of C*w3 ([n][k=d]), (c) PCt packed fp16 transpose ([d][k=n]) via LDS.
__global__ __launch_bounds__(256) void k_prepC(const float* __restrict__ C, const float* __restrict__ w,
                                               float* __restrict__ c1, _Float16* __restrict__ PCt,
                                               _Float16* __restrict__ PCh, _Float16* __restrict__ PCl) {
    __shared__ float Ls[64][65];               // [d][n] fp32 staging for the transpose
    const int bid = blockIdx.x;                // BB * 32 * 8
    const int b   = bid >> 8;
    const int nn0 = ((bid >> 3) & 31) << 6;
    const int dd0 = (bid & 7) << 6;
    const int tid = threadIdx.x;
    const int nl  = tid >> 2;                  // 0..63
    const int dl  = (tid & 3) << 4;            // 0,16,32,48
    const float* w1 = w;
    const float* w3 = w + 2 * DD;
    const size_t crow = ((size_t)(b * NN + nn0 + nl)) * DD + dd0 + dl;
    float4 v[4], u[4], t[4];
#pragma unroll
    for (int p = 0; p < 4; ++p) {
        v[p] = *(const float4*)(C + crow + p * 4);
        u[p] = *(const float4*)(w1 + dd0 + dl + p * 4);
        t[p] = *(const float4*)(w3 + dd0 + dl + p * 4);
    }
    float s = 0.f;
#pragma unroll
    for (int p = 0; p < 4; ++p) s += v[p].x * u[p].x + v[p].y * u[p].y + v[p].z * u[p].z + v[p].w * u[p].w;
    s += __shfl_xor(s, 1); s += __shfl_xor(s, 2);
    if ((tid & 3) == 0) atomicAdd(&c1[b * NN + nn0 + nl], s);
#pragma unroll
    for (int p = 0; p < 4; ++p) {
        Ls[dl + p * 4 + 0][nl] = v[p].x; Ls[dl + p * 4 + 1][nl] = v[p].y;
        Ls[dl + p * 4 + 2][nl] = v[p].z; Ls[dl + p * 4 + 3][nl] = v[p].w;
    }
    const size_t pb = (size_t)b * NN * DD;
#pragma unroll
    for (int q = 0; q < 2; ++q) {              // two 8-wide chunks
        float x[8];
#pragma unroll
        for (int e = 0; e < 8; ++e) {
            const int p = q * 2 + (e >> 2);
            const float* vp = &v[p].x; const float* tp = &t[p].x;
            x[e] = vp[e & 3] * tp[e & 3];
        }
        half8f hh, ll;
#pragma unroll
        for (int e = 0; e < 8; ++e) {
            _Float16 h = (_Float16)x[e]; hh[e] = h;
            ll[e] = (_Float16)((x[e] - (float)h) * 2048.f);
        }
        const int pi = pidx(nn0 + nl, dd0 + dl + q * 8, DD);
        *(half8f*)&PCh[pb + pi] = hh;
        *(half8f*)&PCl[pb + pi] = ll;
    }
    __syncthreads();
    const int d2 = tid >> 2, n2 = (tid & 3) << 4;
    const size_t tb = (size_t)b * DD * NN;
#pragma unroll
    for (int q = 0; q < 2; ++q) {
        const int nc = n2 + q * 8;
        half8f o;
#pragma unroll
        for (int j = 0; j < 8; ++j) o[j] = (_Float16)Ls[d2][nc + j];
        *(half8f*)&PCt[tb + pidx(dd0 + d2, nn0 + nc, NN)] = o;
    }
}

// prepQ: reads Q once; emits q2 partials (Q·w2), PQh/PQl packed split ([m][k=d]),
// PQt packed masked transpose ([d][k=m]).
__global__ __launch_bounds__(256) void k_prepQ(const float* __restrict__ Q, const int* __restrict__ Qmask,
                                               const float* __restrict__ w, float* __restrict__ q2,
                                               _Float16* __restrict__ PQt,
                                               _Float16* __restrict__ PQh, _Float16* __restrict__ PQl) {
    __shared__ float Ls[64][65];               // [d][m], Qmask-zeroed
    const int bid = blockIdx.x;                // BB * 8 * 8
    const int b   = bid >> 6;
    const int rem = bid & 63;
    const int mm0 = (rem >> 3) << 6;
    const int dd0 = (rem & 7) << 6;
    const int tid = threadIdx.x;
    const int ml  = tid >> 2;
    const int dl  = (tid & 3) << 4;
    const float* w2 = w + DD;
    const size_t qrow = ((size_t)(b * MM + mm0 + ml)) * DD + dd0 + dl;
    float4 v[4], u[4];
#pragma unroll
    for (int p = 0; p < 4; ++p) {
        v[p] = *(const float4*)(Q + qrow + p * 4);
        u[p] = *(const float4*)(w2 + dd0 + dl + p * 4);
    }
    float s = 0.f;
#pragma unroll
    for (int p = 0; p < 4; ++p) s += v[p].x * u[p].x + v[p].y * u[p].y + v[p].z * u[p].z + v[p].w * u[p].w;
    s += __shfl_xor(s, 1); s += __shfl_xor(s, 2);
    if ((tid & 3) == 0) atomicAdd(&q2[b * MM + mm0 + ml], s);
    const float z = Qmask[b * MM + mm0 + ml] ? 0.f : 1.f;
#pragma unroll
    for (int p = 0; p < 4; ++p) {
        Ls[dl + p * 4 + 0][ml] = v[p].x * z; Ls[dl + p * 4 + 1][ml] = v[p].y * z;
        Ls[dl + p * 4 + 2][ml] = v[p].z * z; Ls[dl + p * 4 + 3][ml] = v[p].w * z;
    }
    const size_t pb = (size_t)b * MM * DD;
#pragma unroll
    for (int q = 0; q < 2; ++q) {
        float x[8];
#pragma unroll
        for (int e = 0; e < 8; ++e) {
            const int p = q * 2 + (e >> 2);
            const float* vp = &v[p].x;
            x[e] = vp[e & 3];
        }
        half8f hh, ll;
#pragma unroll
        for (int e = 0; e < 8; ++e) {
            _Float16 h = (_Float16)x[e]; hh[e] = h;
            ll[e] = (_Float16)((x[e] - (float)h) * 2048.f);
        }
        const int pi = pidx(mm0 + ml, dd0 + dl + q * 8, DD);
        *(half8f*)&PQh[pb + pi] = hh;
        *(half8f*)&PQl[pb + pi] = ll;
    }
    __syncthreads();
    const int d2 = tid >> 2, m2 = (tid & 3) << 4;
    const size_t tb = (size_t)b * DD * MM;
#pragma unroll
    for (int q = 0; q < 2; ++q) {
        const int mc = m2 + q * 8;
        half8f o;
#pragma unroll
        for (int j = 0; j < 8; ++j) o[j] = (_Float16)Ls[d2][mc + j];
        *(half8f*)&PQt[tb + pidx(dd0 + d2, mm0 + mc, MM)] = o;
    }
}

// k_te: PEt[m][k=n] (packed) = Cmask-zeroed transpose of packed E[n][k=m].
__global__ __launch_bounds__(256) void k_te(const _Float16* __restrict__ PE, const int* __restrict__ Cmask,
                                            _Float16* __restrict__ PEt) {
    __shared__ float Ls[64][65];               // [m][n]
    const int bid = blockIdx.x;                // BB * 32 * 8
    const int b   = bid >> 8;
    const int nn0 = ((bid >> 3) & 31) << 6;
    const int mm0 = (bid & 7) << 6;
    const int tid = threadIdx.x;
    const int nl  = tid >> 2;
    const int ml  = (tid & 3) << 4;
    const float z = Cmask[b * NN + nn0 + nl] ? 0.f : 1.f;
    const size_t eb = (size_t)b * NN * MM;
#pragma unroll
    for (int q = 0; q < 2; ++q) {
        half8f v = *(const half8f*)&PE[eb + pidx(nn0 + nl, mm0 + ml + q * 8, MM)];
#pragma unroll
        for (int j = 0; j < 8; ++j) Ls[ml + q * 8 + j][nl] = (float)v[j] * z;
    }
    __syncthreads();
    const int m2 = tid >> 2, n2 = (tid & 3) << 4;
    const size_t tb = (size_t)b * MM * NN;
#pragma unroll
    for (int q = 0; q < 2; ++q) {
        const int nc = n2 + q * 8;
        half8f o;
#pragma unroll
        for (int j = 0; j < 8; ++j) o[j] = (_Float16)Ls[m2][nc + j];
        *(half8f*)&PEt[tb + pidx(mm0 + m2, nn0 + nc, NN)] = o;
    }
}

// k_sgemm: m97-style LDS double-buffer. Per K-step (2 kc): stage 16 frags/kc via
// global_load_lds, one __syncthreads, 24 MFMAs. S = Ah·Bh + 2^-11(Ah·Bl + Al·Bh);
// E (packed [n][k=m]) = fp16(exp(S + c1 + q2)); masked quantized row/col sums -> rsum/csum.
__global__ __launch_bounds__(256, 2) void k_sgemm(const _Float16* __restrict__ PCh, const _Float16* __restrict__ PCl,
                                                  const _Float16* __restrict__ PQh, const _Float16* __restrict__ PQl,
                                                  const int* __restrict__ Cmask, const int* __restrict__ Qmask,
                                                  const float* __restrict__ c1, const float* __restrict__ q2,
                                                  _Float16* __restrict__ E, float* __restrict__ rsum,
                                                  float* __restrict__ csum) {
    __shared__ _Float16 SB[2][16384];   // 2 x 32KB: (2 kc x 16 frags) x 512 halves
    __shared__ float rowp[128], colp[128], cmz[128], qmz[128], c1s[128], q2s[128];
    const int hw  = blockIdx.x;
    const int bid = ((hw & 7) << 8) | (hw >> 3);   // XCD-chunked swizzle (2048 = 8*256)
    const int b   = bid >> 6;
    const int rem = bid & 63;
    const int n0  = (rem >> 2) << 7;
    const int m0  = (rem & 3) << 7;
    const int tid = threadIdx.x;
    const int lane = tid & 63;
    const int wv   = tid >> 6;
    const int wr = wv >> 1, wc = wv & 1;
    if (tid < 128) {
        rowp[tid] = 0.f; colp[tid] = 0.f;
        cmz[tid] = Cmask[b * NN + n0 + tid] ? 0.f : 1.f;
        c1s[tid] = c1[b * NN + n0 + tid];
    } else {
        const int t = tid - 128;
        qmz[t] = Qmask[b * MM + m0 + t] ? 0.f : 1.f;
        q2s[t] = q2[b * MM + m0 + t];
    }
    const half8f* gAh = (const half8f*)(PCh + (size_t)b * NN * DD + (size_t)n0 * DD) + lane;
    const half8f* gAl = (const half8f*)(PCl + (size_t)b * NN * DD + (size_t)n0 * DD) + lane;
    const half8f* gBh = (const half8f*)(PQh + (size_t)b * MM * DD + (size_t)m0 * DD) + lane;
    const half8f* gBl = (const half8f*)(PQl + (size_t)b * MM * DD + (size_t)m0 * DD) + lane;
    // 8 staging assignments/thread per K-step: f = j*4+wv in 0..31 -> (kcl = f>>4, t = f&15)
    const half8f* srcj[8]; int offj[8];
#pragma unroll
    for (int j = 0; j < 8; ++j) {
        const int f = j * 4 + wv;
        const int kcl = f >> 4, t = f & 15;
        const half8f* s; int p;
        if (t < 4)       { s = gAh; p = t; }
        else if (t < 8)  { s = gAl; p = t - 4; }
        else if (t < 12) { s = gBh; p = t - 8; }
        else             { s = gBl; p = t - 12; }
        srcj[j] = s + kcl * 256 + p * 64;
        offj[j] = (kcl * 16 + t) << 9;
    }
    f32x16 accH[2][2] = {};
    f32x16 accX[2][2] = {};
#pragma unroll
    for (int j = 0; j < 8; ++j) glds16(srcj[j], &SB[0][offj[j]]);
    int cur = 0;
    for (int ks = 0; ks < 16; ++ks) {
        __syncthreads();                       // drains staging of SB[cur] + prior ds_reads
        if (ks + 1 < 16) {
#pragma unroll
            for (int j = 0; j < 8; ++j) glds16(srcj[j] + (ks + 1) * 512, &SB[cur ^ 1][offj[j]]);
        }
#pragma unroll
        for (int kcl = 0; kcl < 2; ++kcl) {
            const _Float16* F = &SB[cur][(kcl << 13) + lane * 8];
            half8f ah0 = *(const half8f*)(F + ((2 * wr) << 9));
            half8f ah1 = *(const half8f*)(F + ((2 * wr + 1) << 9));
            half8f al0 = *(const half8f*)(F + ((4 + 2 * wr) << 9));
            half8f al1 = *(const half8f*)(F + ((5 + 2 * wr) << 9));
            half8f bh0 = *(const half8f*)(F + ((8 + 2 * wc) << 9));
            half8f bh1 = *(const half8f*)(F + ((9 + 2 * wc) << 9));
            half8f bl0 = *(const half8f*)(F + ((12 + 2 * wc) << 9));
            half8f bl1 = *(const half8f*)(F + ((13 + 2 * wc) << 9));
            accH[0][0] = MFMA(ah0, bh0, accH[0][0], 0, 0, 0);
            accH[0][1] = MFMA(ah0, bh1, accH[0][1], 0, 0, 0);
            accH[1][0] = MFMA(ah1, bh0, accH[1][0], 0, 0, 0);
            accH[1][1] = MFMA(ah1, bh1, accH[1][1], 0, 0, 0);
            accX[0][0] = MFMA(ah0, bl0, accX[0][0], 0, 0, 0);
            accX[0][0] = MFMA(al0, bh0, accX[0][0], 0, 0, 0);
            accX[0][1] = MFMA(ah0, bl1, accX[0][1], 0, 0, 0);
            accX[0][1] = MFMA(al0, bh1, accX[0][1], 0, 0, 0);
            accX[1][0] = MFMA(ah1, bl0, accX[1][0], 0, 0, 0);
            accX[1][0] = MFMA(al1, bh0, accX[1][0], 0, 0, 0);
            accX[1][1] = MFMA(ah1, bl1, accX[1][1], 0, 0, 0);
            accX[1][1] = MFMA(al1, bh1, accX[1][1], 0, 0, 0);
        }
        cur ^= 1;
    }
    // epilogue: C/D layout col=lane&31, row=(r&3)+8*(r>>2)+4*(lane>>5) [m74/m101-verified]
    const float inv2k = 4.8828125e-4f;  // 2^-11
    const int mcol0 = wc * 64 + (lane & 31);
    const float qz0 = qmz[mcol0], qz1 = qmz[mcol0 + 32];
    const float q2v0 = q2s[mcol0], q2v1 = q2s[mcol0 + 32];
    const int hi4 = (lane >> 5) << 2;
    const size_t ebase = (size_t)b * NN * MM + (size_t)n0 * MM;
    const int kp0 = kpart(m0 + mcol0);
    const int kp1 = kpart(m0 + mcol0 + 32);
    float colacc0 = 0.f, colacc1 = 0.f;
#pragma unroll
    for (int i = 0; i < 2; ++i) {
#pragma unroll
        for (int r = 0; r < 16; ++r) {
            const int nloc = wr * 64 + i * 32 + (r & 3) + ((r >> 2) << 3) + hi4;
            const float base = c1s[nloc];
            float S0 = accH[i][0][r] + accX[i][0][r] * inv2k + base + q2v0;
            float S1 = accH[i][1][r] + accX[i][1][r] * inv2k + base + q2v1;
            float e0 = __expf(S0), e1 = __expf(S1);
            _Float16 h0 = (_Float16)e0, h1 = (_Float16)e1;
            float eq0 = (float)h0, eq1 = (float)h1;
            const int rp = (((nloc >> 5) & 3) << 9) + ((nloc & 31) << 3);
            E[ebase + rp + kp0] = h0;
            E[ebase + rp + kp1] = h1;
            const float cz = cmz[nloc];
            colacc0 += eq0 * cz;
            colacc1 += eq1 * cz;
            float rv = eq0 * qz0 + eq1 * qz1;
            rv += __shfl_xor(rv, 1);  rv += __shfl_xor(rv, 2);
            rv += __shfl_xor(rv, 4);  rv += __shfl_xor(rv, 8);
            rv += __shfl_xor(rv, 16);
            if ((lane & 31) == 0) atomicAdd(&rowp[nloc], rv);
        }
    }
    atomicAdd(&colp[mcol0], colacc0);
    atomicAdd(&colp[mcol0 + 32], colacc1);
    __syncthreads();
    if (tid < 128) atomicAdd(&rsum[b * NN + n0 + tid], rowp[tid]);
    else atomicAdd(&csum[b * MM + m0 + tid - 128], colp[tid - 128]);
}

// k_T: LDS double-buffer, K-step = 4 kc (8 frags/kc). Tt[d][k=m] (packed) =
// fp16((1/csum[m])·qz[m]·Σ_n Ct[d,n]·Et[m,n]).
__global__ __launch_bounds__(256, 2) void k_T(const _Float16* __restrict__ PCt,
                                              const _Float16* __restrict__ PEt,
                                              const float* __restrict__ csum,
                                              const int* __restrict__ Qmask,
                                              _Float16* __restrict__ Tt) {
    __shared__ _Float16 SB[2][16384];   // 2 x 32KB: (4 kc x 8 frags) x 512 halves
    const int hw  = blockIdx.x;                    // 512
    const int bid = ((hw & 7) << 6) | (hw >> 3);   // bijective (512 = 8*64)
    const int b   = bid >> 4;
    const int rem = bid & 15;
    const int d0  = (rem >> 2) << 7;
    const int m0  = (rem & 3) << 7;
    const int tid = threadIdx.x;
    const int lane = tid & 63;
    const int wv   = tid >> 6;
    const int wr = wv >> 1, wc = wv & 1;
    const half8f* gA = (const half8f*)(PCt + (size_t)b * DD * NN + (size_t)d0 * NN) + lane;
    const half8f* gB = (const half8f*)(PEt + (size_t)b * MM * NN + (size_t)m0 * NN) + lane;
    const half8f* srcj[8]; int offj[8];
#pragma unroll
    for (int j = 0; j < 8; ++j) {
        const int f = j * 4 + wv;            // 0..31
        const int kcl = f >> 3, t = f & 7;
        const half8f* s; int p;
        if (t < 4) { s = gA; p = t; } else { s = gB; p = t - 4; }
        srcj[j] = s + kcl * 256 + p * 64;
        offj[j] = (kcl * 8 + t) << 9;
    }
    f32x16 acc[2][2] = {};
#pragma unroll
    for (int j = 0; j < 8; ++j) glds16(srcj[j], &SB[0][offj[j]]);
    int cur = 0;
    for (int ks = 0; ks < 32; ++ks) {
        __syncthreads();
        if (ks + 1 < 32) {
#pragma unroll
            for (int j = 0; j < 8; ++j) glds16(srcj[j] + (ks + 1) * 1024, &SB[cur ^ 1][offj[j]]);
        }
#pragma unroll
        for (int kcl = 0; kcl < 4; ++kcl) {
            const _Float16* F = &SB[cur][(kcl << 12) + lane * 8];
            half8f a0 = *(const half8f*)(F + ((2 * wr) << 9));
            half8f a1 = *(const half8f*)(F + ((2 * wr + 1) << 9));
            half8f b0 = *(const half8f*)(F + ((4 + 2 * wc) << 9));
            half8f b1 = *(const half8f*)(F + ((5 + 2 * wc) << 9));
            acc[0][0] = MFMA(a0, b0, acc[0][0], 0, 0, 0);
            acc[0][1] = MFMA(a0, b1, acc[0][1], 0, 0, 0);
            acc[1][0] = MFMA(a1, b0, acc[1][0], 0, 0, 0);
            acc[1][1] = MFMA(a1, b1, acc[1][1], 0, 0, 0);
        }
        cur ^= 1;
    }
    const int mc0 = m0 + wc * 64 + (lane & 31);
    const float s0 = (Qmask[b * MM + mc0]      ? 0.f : 1.f) / csum[b * MM + mc0];
    const float s1 = (Qmask[b * MM + mc0 + 32] ? 0.f : 1.f) / csum[b * MM + mc0 + 32];
    const int hi4 = (lane >> 5) << 2;
    const size_t tbase = (size_t)b * DD * MM + (size_t)d0 * MM;
    const int kp0 = kpart(mc0);
    const int kp1 = kpart(mc0 + 32);
#pragma unroll
    for (int i = 0; i < 2; ++i) {
#pragma unroll
        for (int r = 0; r < 16; ++r) {
            const int dloc = wr * 64 + i * 32 + (r & 3) + ((r >> 2) << 3) + hi4;
            const int rp = (((dloc >> 5) & 3) << 9) + ((dloc & 31) << 3);
            Tt[tbase + rp + kp0] = (_Float16)(acc[i][0][r] * s0);
            Tt[tbase + rp + kp1] = (_Float16)(acc[i][1][r] * s1);
        }
    }
}

// k_AB: LDS double-buffer, K-step = 2 kc (12 frags/kc: E x4, Qt x4, Tt x4).
// A[n][d] = (1/rsum[n])·Σ_m E[n,m]·Qt[d,m]; Bout likewise with Tt.
__global__ __launch_bounds__(256, 2) void k_AB(const _Float16* __restrict__ E,
                                               const _Float16* __restrict__ PQt,
                                               const _Float16* __restrict__ Tt,
                                               const float* __restrict__ rsum,
                                               float* __restrict__ outA, float* __restrict__ outB) {
    __shared__ _Float16 SB[2][12288];   // 2 x 24KB: (2 kc x 12 frags) x 512 halves
    const int hw  = blockIdx.x;
    const int bid = ((hw & 7) << 8) | (hw >> 3);
    const int b   = bid >> 6;
    const int rem = bid & 63;
    const int n0  = (rem >> 2) << 7;
    const int d0  = (rem & 3) << 7;
    const int tid = threadIdx.x;
    const int lane = tid & 63;
    const int wv   = tid >> 6;
    const int wr = wv >> 1, wc = wv & 1;
    const half8f* gE = (const half8f*)(E   + (size_t)b * NN * MM + (size_t)n0 * MM) + lane;
    const half8f* gQ = (const half8f*)(PQt + (size_t)b * DD * MM + (size_t)d0 * MM) + lane;
    const half8f* gT = (const half8f*)(Tt  + (size_t)b * DD * MM + (size_t)d0 * MM) + lane;
    const half8f* srcj[6]; int offj[6];
#pragma unroll
    for (int j = 0; j < 6; ++j) {
        const int f = j * 4 + wv;            // 0..23
        const int kcl = (f >= 12) ? 1 : 0;
        const int t = f - kcl * 12;
        const half8f* s; int p;
        if (t < 4)      { s = gE; p = t; }
        else if (t < 8) { s = gQ; p = t - 4; }
        else            { s = gT; p = t - 8; }
        srcj[j] = s + kcl * 256 + p * 64;
        offj[j] = (kcl * 12 + t) << 9;
    }
    f32x16 accA[2][2] = {};
    f32x16 accB[2][2] = {};
#pragma unroll
    for (int j = 0; j < 6; ++j) glds16(srcj[j], &SB[0][offj[j]]);
    int cur = 0;
    for (int ks = 0; ks < 16; ++ks) {
        __syncthreads();
        if (ks + 1 < 16) {
#pragma unroll
            for (int j = 0; j < 6; ++j) glds16(srcj[j] + (ks + 1) * 512, &SB[cur ^ 1][offj[j]]);
        }
#pragma unroll
        for (int kcl = 0; kcl < 2; ++kcl) {
            const _Float16* F = &SB[cur][kcl * 6144 + lane * 8];
            half8f e0 = *(const half8f*)(F + ((2 * wr) << 9));
            half8f e1 = *(const half8f*)(F + ((2 * wr + 1) << 9));
            half8f q0 = *(const half8f*)(F + ((4 + 2 * wc) << 9));
            half8f q1 = *(const half8f*)(F + ((5 + 2 * wc) << 9));
            half8f t0 = *(const half8f*)(F + ((8 + 2 * wc) << 9));
            half8f t1 = *(const half8f*)(F + ((9 + 2 * wc) << 9));
            accA[0][0] = MFMA(e0, q0, accA[0][0], 0, 0, 0);
            accA[0][1] = MFMA(e0, q1, accA[0][1], 0, 0, 0);
            accA[1][0] = MFMA(e1, q0, accA[1][0], 0, 0, 0);
            accA[1][1] = MFMA(e1, q1, accA[1][1], 0, 0, 0);
            accB[0][0] = MFMA(e0, t0, accB[0][0], 0, 0, 0);
            accB[0][1] = MFMA(e0, t1, accB[0][1], 0, 0, 0);
            accB[1][0] = MFMA(e1, t0, accB[1][0], 0, 0, 0);
            accB[1][1] = MFMA(e1, t1, accB[1][1], 0, 0, 0);
        }
        cur ^= 1;
    }
    const int dc = d0 + wc * 64 + (lane & 31);
#pragma unroll
    for (int i = 0; i < 2; ++i) {
#pragma unroll
        for (int r = 0; r < 16; ++r) {
            const int row = (r & 3) + ((r >> 2) << 3) + ((lane >> 5) << 2);
            const int n = n0 + wr * 64 + i * 32 + row;
            const float inv = __builtin_amdgcn_rcpf(rsum[b * NN + n]);
            const size_t o = ((size_t)(b * NN + n)) * DD + dc;
            outA[o]      = accA[i][0][r] * inv;
            outA[o + 32] = accA[i][1][r] * inv;
            outB[o]      = accB[i][0][r] * inv;
            outB[o + 32] = accB[i][1][r] * inv;
        }
    }
}

extern "C" void kernel_launch(void* const* d_in, const int* in_sizes, int n_in,
                              void* d_out, int out_size, void* d_ws, size_t ws_size,
                              hipStream_t stream) {
    const float* C = (const float*)d_in[0];
    const float* Q = (const float*)d_in[1];
    const int* Cmask = (const int*)d_in[2];
    const int* Qmask = (const int*)d_in[3];
    const float* w  = (const float*)d_in[4];

    const size_t BNM = (size_t)BB * NN * MM;   // 33.55M halves
    const size_t BMD = (size_t)BB * MM * DD;   // 8.39M halves
    const size_t BND = (size_t)BB * NN * DD;   // 33.55M halves
    const size_t BN  = (size_t)BB * NN;
    const size_t BM  = (size_t)BB * MM;

    // d_ws: E (packed), Tt (packed), PQt (packed) + fp32 vectors (~101 MB).
    _Float16* E   = (_Float16*)d_ws;
    _Float16* Tt  = E + BNM;
    _Float16* PQt = Tt + BMD;
    float* c1   = (float*)(PQt + BMD);
    float* q2   = c1 + BN;
    float* rsum = q2 + BM;
    float* csum = rsum + BN;

    // Scratch in d_out (268.4 MB): PCt|PCh|PCl|PQh|PQl = 67+67+67+16.8+16.8 = 234.9 MB.
    // PCh/PCl/PQh/PQl dead after k_sgemm; PEt reuses the PCh slot; PCt/PEt dead after k_T;
    // k_AB then overwrites d_out with outA/outB.
    _Float16* PCt = (_Float16*)d_out;
    _Float16* PCh = PCt + BND;
    _Float16* PCl = PCh + BND;
    _Float16* PQh = PCl + BND;
    _Float16* PQl = PQh + BMD;
    _Float16* PEt = PCh;   // reuse after k_sgemm

    hipMemsetAsync(c1, 0, 2 * (BN + BM) * sizeof(float), stream);  // c1,q2,rsum,csum contiguous

    k_prepQ<<<BB * 64, 256, 0, stream>>>(Q, Qmask, w, q2, PQt, PQh, PQl);
    k_prepC<<<BB * 256, 256, 0, stream>>>(C, w, c1, PCt, PCh, PCl);
    k_sgemm<<<2048, 256, 0, stream>>>(PCh, PCl, PQh, PQl, Cmask, Qmask, c1, q2, E, rsum, csum);
    k_te<<<BB * 256, 256, 0, stream>>>(E, Cmask, PEt);
    k_T<<<512, 256, 0, stream>>>(PCt, PEt, csum, Qmask, Tt);
    k_AB<<<2048, 256, 0, stream>>>(E, PQt, Tt, rsum,
                                   (float*)d_out, (float*)d_out + BND);
}

// Round 7
// 655.821 us; speedup vs baseline: 1.3430x; 1.1093x over previous
//
#include <hip/hip_runtime.h>

#define BB 32
#define NN 2048
#define MM 512
#define DD 512

typedef _Float16 half8f __attribute__((ext_vector_type(8)));
typedef float    f32x16 __attribute__((ext_vector_type(16)));

#define MFMA __builtin_amdgcn_mfma_f32_32x32x16_f16

// Packed fragment layout for a row-major [R][K] matrix (per-b slice), R%128==0, K%16==0.
// Fragment (32 rows x 16 k): lane l holds row r32*32+(l&31), halves kc*16+(l>>5)*8 .. +8,
// stored at panel*128K + kc*2048 + r32*512 + l*8 -> one fully-coalesced 1KB wave load,
// and a global_load_lds-compatible blob (wave-uniform LDS base + lane*16).
// pidx(r,k) decomposes as mpart(r) + kpart(k):
//   mpart(r) = (r>>7)*(K<<7) + (((r>>5)&3)<<9) + ((r&31)<<3)
//   kpart(k) = ((k>>4)<<11) + (((k>>3)&1)<<8) + (k&7)
__device__ __forceinline__ int pidx(int r, int k, int K) {
    return (r >> 7) * (K << 7) + ((k >> 4) << 11) + (((r >> 5) & 3) << 9)
         + (((r & 31) + (((k >> 3) & 1) << 5)) << 3) + (k & 7);
}
__device__ __forceinline__ int kpart(int k) {
    return ((k >> 4) << 11) + (((k >> 3) & 1) << 8) + (k & 7);
}

// 16B async global->LDS (DMA, no VGPR roundtrip). LDS dest must be wave-uniform;
// HW adds lane*16. Global src is per-lane.
__device__ __forceinline__ void glds16(const void* g, void* l) {
    __builtin_amdgcn_global_load_lds(
        (const __attribute__((address_space(1))) unsigned int*)g,
        (__attribute__((address_space(3))) unsigned int*)l, 16, 0, 0);
}

// prepC: reads C once; emits (a) c1 partial dots (C·w1, atomics), (b) PCh packed fp16
// of C*w3 ([n][k=d]), (c) PCt packed fp16 transpose ([d][k=n]) via LDS.
__global__ __launch_bounds__(256) void k_prepC(const float* __restrict__ C, const float* __restrict__ w,
                                               float* __restrict__ c1, _Float16* __restrict__ PCt,
                                               _Float16* __restrict__ PCh) {
    __shared__ float Ls[64][65];               // [d][n] fp32 staging for the transpose
    const int bid = blockIdx.x;                // BB * 32 * 8
    const int b   = bid >> 8;
    const int nn0 = ((bid >> 3) & 31) << 6;
    const int dd0 = (bid & 7) << 6;
    const int tid = threadIdx.x;
    const int nl  = tid >> 2;                  // 0..63
    const int dl  = (tid & 3) << 4;            // 0,16,32,48
    const float* w1 = w;
    const float* w3 = w + 2 * DD;
    const size_t crow = ((size_t)(b * NN + nn0 + nl)) * DD + dd0 + dl;
    float4 v[4], u[4], t[4];
#pragma unroll
    for (int p = 0; p < 4; ++p) {
        v[p] = *(const float4*)(C + crow + p * 4);
        u[p] = *(const float4*)(w1 + dd0 + dl + p * 4);
        t[p] = *(const float4*)(w3 + dd0 + dl + p * 4);
    }
    float s = 0.f;
#pragma unroll
    for (int p = 0; p < 4; ++p) s += v[p].x * u[p].x + v[p].y * u[p].y + v[p].z * u[p].z + v[p].w * u[p].w;
    s += __shfl_xor(s, 1); s += __shfl_xor(s, 2);
    if ((tid & 3) == 0) atomicAdd(&c1[b * NN + nn0 + nl], s);
#pragma unroll
    for (int p = 0; p < 4; ++p) {
        Ls[dl + p * 4 + 0][nl] = v[p].x; Ls[dl + p * 4 + 1][nl] = v[p].y;
        Ls[dl + p * 4 + 2][nl] = v[p].z; Ls[dl + p * 4 + 3][nl] = v[p].w;
    }
    const size_t pb = (size_t)b * NN * DD;
#pragma unroll
    for (int q = 0; q < 2; ++q) {              // two 8-wide chunks
        half8f hh;
#pragma unroll
        for (int e = 0; e < 8; ++e) {
            const int p = q * 2 + (e >> 2);
            const float* vp = &v[p].x; const float* tp = &t[p].x;
            hh[e] = (_Float16)(vp[e & 3] * tp[e & 3]);
        }
        *(half8f*)&PCh[pb + pidx(nn0 + nl, dd0 + dl + q * 8, DD)] = hh;
    }
    __syncthreads();
    const int d2 = tid >> 2, n2 = (tid & 3) << 4;
    const size_t tb = (size_t)b * DD * NN;
#pragma unroll
    for (int q = 0; q < 2; ++q) {
        const int nc = n2 + q * 8;
        half8f o;
#pragma unroll
        for (int j = 0; j < 8; ++j) o[j] = (_Float16)Ls[d2][nc + j];
        *(half8f*)&PCt[tb + pidx(dd0 + d2, nn0 + nc, NN)] = o;
    }
}

// prepQ: reads Q once; emits q2 partials (Q·w2), PQh packed fp16 ([m][k=d]),
// PQt packed masked transpose ([d][k=m]).
__global__ __launch_bounds__(256) void k_prepQ(const float* __restrict__ Q, const int* __restrict__ Qmask,
                                               const float* __restrict__ w, float* __restrict__ q2,
                                               _Float16* __restrict__ PQt, _Float16* __restrict__ PQh) {
    __shared__ float Ls[64][65];               // [d][m], Qmask-zeroed
    const int bid = blockIdx.x;                // BB * 8 * 8
    const int b   = bid >> 6;
    const int rem = bid & 63;
    const int mm0 = (rem >> 3) << 6;
    const int dd0 = (rem & 7) << 6;
    const int tid = threadIdx.x;
    const int ml  = tid >> 2;
    const int dl  = (tid & 3) << 4;
    const float* w2 = w + DD;
    const size_t qrow = ((size_t)(b * MM + mm0 + ml)) * DD + dd0 + dl;
    float4 v[4], u[4];
#pragma unroll
    for (int p = 0; p < 4; ++p) {
        v[p] = *(const float4*)(Q + qrow + p * 4);
        u[p] = *(const float4*)(w2 + dd0 + dl + p * 4);
    }
    float s = 0.f;
#pragma unroll
    for (int p = 0; p < 4; ++p) s += v[p].x * u[p].x + v[p].y * u[p].y + v[p].z * u[p].z + v[p].w * u[p].w;
    s += __shfl_xor(s, 1); s += __shfl_xor(s, 2);
    if ((tid & 3) == 0) atomicAdd(&q2[b * MM + mm0 + ml], s);
    const float z = Qmask[b * MM + mm0 + ml] ? 0.f : 1.f;
#pragma unroll
    for (int p = 0; p < 4; ++p) {
        Ls[dl + p * 4 + 0][ml] = v[p].x * z; Ls[dl + p * 4 + 1][ml] = v[p].y * z;
        Ls[dl + p * 4 + 2][ml] = v[p].z * z; Ls[dl + p * 4 + 3][ml] = v[p].w * z;
    }
    const size_t pb = (size_t)b * MM * DD;
#pragma unroll
    for (int q = 0; q < 2; ++q) {
        half8f hh;
#pragma unroll
        for (int e = 0; e < 8; ++e) {
            const int p = q * 2 + (e >> 2);
            const float* vp = &v[p].x;
            hh[e] = (_Float16)vp[e & 3];
        }
        *(half8f*)&PQh[pb + pidx(mm0 + ml, dd0 + dl + q * 8, DD)] = hh;
    }
    __syncthreads();
    const int d2 = tid >> 2, m2 = (tid & 3) << 4;
    const size_t tb = (size_t)b * DD * MM;
#pragma unroll
    for (int q = 0; q < 2; ++q) {
        const int mc = m2 + q * 8;
        half8f o;
#pragma unroll
        for (int j = 0; j < 8; ++j) o[j] = (_Float16)Ls[d2][mc + j];
        *(half8f*)&PQt[tb + pidx(dd0 + d2, mm0 + mc, MM)] = o;
    }
}

// k_sgemm: single fp16 GEMM (no split), LDS double-buffer via global_load_lds.
// Per K-step (2 kc): stage 16 frags, one barrier, 8 MFMAs/wave.
// S = (C*w3)·Q^T + c1 + q2;  E (packed [n][k=m]) = fp16(exp(S));
// PEt (packed [m][k=n]) = Cmask-zeroed E (k_te folded in);
// masked quantized row/col sums -> rsum/csum.
__global__ __launch_bounds__(256, 3) void k_sgemm(const _Float16* __restrict__ PCh,
                                                  const _Float16* __restrict__ PQh,
                                                  const int* __restrict__ Cmask, const int* __restrict__ Qmask,
                                                  const float* __restrict__ c1, const float* __restrict__ q2,
                                                  _Float16* __restrict__ E, _Float16* __restrict__ PEt,
                                                  float* __restrict__ rsum, float* __restrict__ csum) {
    __shared__ _Float16 SB[2][8192];   // 2 x 16KB: (2 kc x 8 frags) x 512 halves
    __shared__ float rowp[128], colp[128], cmz[128], qmz[128], c1s[128], q2s[128];
    const int hw  = blockIdx.x;
    const int bid = ((hw & 7) << 8) | (hw >> 3);   // XCD-chunked swizzle (2048 = 8*256)
    const int b   = bid >> 6;
    const int rem = bid & 63;
    const int n0  = (rem >> 2) << 7;
    const int m0  = (rem & 3) << 7;
    const int tid = threadIdx.x;
    const int lane = tid & 63;
    const int wv   = tid >> 6;
    const int wr = wv >> 1, wc = wv & 1;
    if (tid < 128) {
        rowp[tid] = 0.f; colp[tid] = 0.f;
        cmz[tid] = Cmask[b * NN + n0 + tid] ? 0.f : 1.f;
        c1s[tid] = c1[b * NN + n0 + tid];
    } else {
        const int t = tid - 128;
        qmz[t] = Qmask[b * MM + m0 + t] ? 0.f : 1.f;
        q2s[t] = q2[b * MM + m0 + t];
    }
    const half8f* gA = (const half8f*)(PCh + (size_t)b * NN * DD + (size_t)n0 * DD) + lane;
    const half8f* gB = (const half8f*)(PQh + (size_t)b * MM * DD + (size_t)m0 * DD) + lane;
    // 4 staging assignments/thread per K-step: f = j*4+wv in 0..15 -> (kcl = f>>3, t = f&7)
    const half8f* srcj[4]; int offj[4];
#pragma unroll
    for (int j = 0; j < 4; ++j) {
        const int f = j * 4 + wv;
        const int kcl = f >> 3, t = f & 7;
        srcj[j] = (t < 4 ? gA + t * 64 : gB + (t - 4) * 64) + kcl * 256;
        offj[j] = (kcl * 8 + t) << 9;
    }
    f32x16 acc[2][2] = {};
#pragma unroll
    for (int j = 0; j < 4; ++j) glds16(srcj[j], &SB[0][offj[j]]);
    int cur = 0;
    for (int ks = 0; ks < 16; ++ks) {
        __syncthreads();                       // drains staging of SB[cur] + prior ds_reads
        if (ks + 1 < 16) {
#pragma unroll
            for (int j = 0; j < 4; ++j) glds16(srcj[j] + (ks + 1) * 512, &SB[cur ^ 1][offj[j]]);
        }
#pragma unroll
        for (int kcl = 0; kcl < 2; ++kcl) {
            const _Float16* F = &SB[cur][(kcl << 12) + lane * 8];
            half8f a0 = *(const half8f*)(F + ((2 * wr) << 9));
            half8f a1 = *(const half8f*)(F + ((2 * wr + 1) << 9));
            half8f b0 = *(const half8f*)(F + ((4 + 2 * wc) << 9));
            half8f b1 = *(const half8f*)(F + ((5 + 2 * wc) << 9));
            acc[0][0] = MFMA(a0, b0, acc[0][0], 0, 0, 0);
            acc[0][1] = MFMA(a0, b1, acc[0][1], 0, 0, 0);
            acc[1][0] = MFMA(a1, b0, acc[1][0], 0, 0, 0);
            acc[1][1] = MFMA(a1, b1, acc[1][1], 0, 0, 0);
        }
        cur ^= 1;
    }
    // epilogue: C/D layout col=lane&31, row=(r&3)+8*(r>>2)+4*(lane>>5) [m74/m101-verified]
    const int mcol0 = wc * 64 + (lane & 31);
    const float qz0 = qmz[mcol0], qz1 = qmz[mcol0 + 32];
    const float q2v0 = q2s[mcol0], q2v1 = q2s[mcol0 + 32];
    const int hi4 = (lane >> 5) << 2;
    const size_t ebase = (size_t)b * NN * MM + (size_t)n0 * MM;
    const int kp0 = kpart(m0 + mcol0);
    const int kp1 = kpart(m0 + mcol0 + 32);
    // PEt ([m][k=n] packed): index = petb + mpart(m) + kpart(n)
    const size_t petb = (size_t)b * MM * NN;
    const int mp0 = ((m0 + mcol0) >> 7) * (NN << 7) + (((mcol0 >> 5) & 3) << 9) + ((lane & 31) << 3);
    const int mp1 = ((m0 + mcol0 + 32) >> 7) * (NN << 7) + ((((mcol0 + 32) >> 5) & 3) << 9) + ((lane & 31) << 3);
    float colacc0 = 0.f, colacc1 = 0.f;
#pragma unroll
    for (int i = 0; i < 2; ++i) {
#pragma unroll
        for (int r = 0; r < 16; ++r) {
            const int nloc = wr * 64 + i * 32 + (r & 3) + ((r >> 2) << 3) + hi4;
            const float base = c1s[nloc];
            float S0 = acc[i][0][r] + base + q2v0;
            float S1 = acc[i][1][r] + base + q2v1;
            float e0 = __expf(S0), e1 = __expf(S1);
            _Float16 h0 = (_Float16)e0, h1 = (_Float16)e1;
            float eq0 = (float)h0, eq1 = (float)h1;
            const int rp = (((nloc >> 5) & 3) << 9) + ((nloc & 31) << 3);
            E[ebase + rp + kp0] = h0;
            E[ebase + rp + kp1] = h1;
            const float cz = cmz[nloc];
            const int kpn = kpart(n0 + nloc);
            PEt[petb + mp0 + kpn] = (_Float16)(eq0 * cz);   // exact: fp16 x {0,1}
            PEt[petb + mp1 + kpn] = (_Float16)(eq1 * cz);
            colacc0 += eq0 * cz;
            colacc1 += eq1 * cz;
            float rv = eq0 * qz0 + eq1 * qz1;
            rv += __shfl_xor(rv, 1);  rv += __shfl_xor(rv, 2);
            rv += __shfl_xor(rv, 4);  rv += __shfl_xor(rv, 8);
            rv += __shfl_xor(rv, 16);
            if ((lane & 31) == 0) atomicAdd(&rowp[nloc], rv);
        }
    }
    atomicAdd(&colp[mcol0], colacc0);
    atomicAdd(&colp[mcol0 + 32], colacc1);
    __syncthreads();
    if (tid < 128) atomicAdd(&rsum[b * NN + n0 + tid], rowp[tid]);
    else atomicAdd(&csum[b * MM + m0 + tid - 128], colp[tid - 128]);
}

// k_T: LDS double-buffer, K-step = 4 kc (8 frags/kc). Tt[d][k=m] (packed) =
// fp16((1/csum[m])·qz[m]·Σ_n Ct[d,n]·Et[m,n]).
__global__ __launch_bounds__(256, 2) void k_T(const _Float16* __restrict__ PCt,
                                              const _Float16* __restrict__ PEt,
                                              const float* __restrict__ csum,
                                              const int* __restrict__ Qmask,
                                              _Float16* __restrict__ Tt) {
    __shared__ _Float16 SB[2][16384];   // 2 x 32KB: (4 kc x 8 frags) x 512 halves
    const int hw  = blockIdx.x;                    // 512
    const int bid = ((hw & 7) << 6) | (hw >> 3);   // bijective (512 = 8*64)
    const int b   = bid >> 4;
    const int rem = bid & 15;
    const int d0  = (rem >> 2) << 7;
    const int m0  = (rem & 3) << 7;
    const int tid = threadIdx.x;
    const int lane = tid & 63;
    const int wv   = tid >> 6;
    const int wr = wv >> 1, wc = wv & 1;
    const half8f* gA = (const half8f*)(PCt + (size_t)b * DD * NN + (size_t)d0 * NN) + lane;
    const half8f* gB = (const half8f*)(PEt + (size_t)b * MM * NN + (size_t)m0 * NN) + lane;
    const half8f* srcj[8]; int offj[8];
#pragma unroll
    for (int j = 0; j < 8; ++j) {
        const int f = j * 4 + wv;            // 0..31
        const int kcl = f >> 3, t = f & 7;
        const half8f* s; int p;
        if (t < 4) { s = gA; p = t; } else { s = gB; p = t - 4; }
        srcj[j] = s + kcl * 256 + p * 64;
        offj[j] = (kcl * 8 + t) << 9;
    }
    f32x16 acc[2][2] = {};
#pragma unroll
    for (int j = 0; j < 8; ++j) glds16(srcj[j], &SB[0][offj[j]]);
    int cur = 0;
    for (int ks = 0; ks < 32; ++ks) {
        __syncthreads();
        if (ks + 1 < 32) {
#pragma unroll
            for (int j = 0; j < 8; ++j) glds16(srcj[j] + (ks + 1) * 1024, &SB[cur ^ 1][offj[j]]);
        }
#pragma unroll
        for (int kcl = 0; kcl < 4; ++kcl) {
            const _Float16* F = &SB[cur][(kcl << 12) + lane * 8];
            half8f a0 = *(const half8f*)(F + ((2 * wr) << 9));
            half8f a1 = *(const half8f*)(F + ((2 * wr + 1) << 9));
            half8f b0 = *(const half8f*)(F + ((4 + 2 * wc) << 9));
            half8f b1 = *(const half8f*)(F + ((5 + 2 * wc) << 9));
            acc[0][0] = MFMA(a0, b0, acc[0][0], 0, 0, 0);
            acc[0][1] = MFMA(a0, b1, acc[0][1], 0, 0, 0);
            acc[1][0] = MFMA(a1, b0, acc[1][0], 0, 0, 0);
            acc[1][1] = MFMA(a1, b1, acc[1][1], 0, 0, 0);
        }
        cur ^= 1;
    }
    const int mc0 = m0 + wc * 64 + (lane & 31);
    const float s0 = (Qmask[b * MM + mc0]      ? 0.f : 1.f) / csum[b * MM + mc0];
    const float s1 = (Qmask[b * MM + mc0 + 32] ? 0.f : 1.f) / csum[b * MM + mc0 + 32];
    const int hi4 = (lane >> 5) << 2;
    const size_t tbase = (size_t)b * DD * MM + (size_t)d0 * MM;
    const int kp0 = kpart(mc0);
    const int kp1 = kpart(mc0 + 32);
#pragma unroll
    for (int i = 0; i < 2; ++i) {
#pragma unroll
        for (int r = 0; r < 16; ++r) {
            const int dloc = wr * 64 + i * 32 + (r & 3) + ((r >> 2) << 3) + hi4;
            const int rp = (((dloc >> 5) & 3) << 9) + ((dloc & 31) << 3);
            Tt[tbase + rp + kp0] = (_Float16)(acc[i][0][r] * s0);
            Tt[tbase + rp + kp1] = (_Float16)(acc[i][1][r] * s1);
        }
    }
}

// k_AB: LDS double-buffer, K-step = 2 kc (12 frags/kc: E x4, Qt x4, Tt x4).
// A[n][d] = (1/rsum[n])·Σ_m E[n,m]·Qt[d,m]; Bout likewise with Tt.
__global__ __launch_bounds__(256, 2) void k_AB(const _Float16* __restrict__ E,
                                               const _Float16* __restrict__ PQt,
                                               const _Float16* __restrict__ Tt,
                                               const float* __restrict__ rsum,
                                               float* __restrict__ outA, float* __restrict__ outB) {
    __shared__ _Float16 SB[2][12288];   // 2 x 24KB: (2 kc x 12 frags) x 512 halves
    const int hw  = blockIdx.x;
    const int bid = ((hw & 7) << 8) | (hw >> 3);
    const int b   = bid >> 6;
    const int rem = bid & 63;
    const int n0  = (rem >> 2) << 7;
    const int d0  = (rem & 3) << 7;
    const int tid = threadIdx.x;
    const int lane = tid & 63;
    const int wv   = tid >> 6;
    const int wr = wv >> 1, wc = wv & 1;
    const half8f* gE = (const half8f*)(E   + (size_t)b * NN * MM + (size_t)n0 * MM) + lane;
    const half8f* gQ = (const half8f*)(PQt + (size_t)b * DD * MM + (size_t)d0 * MM) + lane;
    const half8f* gT = (const half8f*)(Tt  + (size_t)b * DD * MM + (size_t)d0 * MM) + lane;
    const half8f* srcj[6]; int offj[6];
#pragma unroll
    for (int j = 0; j < 6; ++j) {
        const int f = j * 4 + wv;            // 0..23
        const int kcl = (f >= 12) ? 1 : 0;
        const int t = f - kcl * 12;
        const half8f* s; int p;
        if (t < 4)      { s = gE; p = t; }
        else if (t < 8) { s = gQ; p = t - 4; }
        else            { s = gT; p = t - 8; }
        srcj[j] = s + kcl * 256 + p * 64;
        offj[j] = (kcl * 12 + t) << 9;
    }
    f32x16 accA[2][2] = {};
    f32x16 accB[2][2] = {};
#pragma unroll
    for (int j = 0; j < 6; ++j) glds16(srcj[j], &SB[0][offj[j]]);
    int cur = 0;
    for (int ks = 0; ks < 16; ++ks) {
        __syncthreads();
        if (ks + 1 < 16) {
#pragma unroll
            for (int j = 0; j < 6; ++j) glds16(srcj[j] + (ks + 1) * 512, &SB[cur ^ 1][offj[j]]);
        }
#pragma unroll
        for (int kcl = 0; kcl < 2; ++kcl) {
            const _Float16* F = &SB[cur][kcl * 6144 + lane * 8];
            half8f e0 = *(const half8f*)(F + ((2 * wr) << 9));
            half8f e1 = *(const half8f*)(F + ((2 * wr + 1) << 9));
            half8f q0 = *(const half8f*)(F + ((4 + 2 * wc) << 9));
            half8f q1 = *(const half8f*)(F + ((5 + 2 * wc) << 9));
            half8f t0 = *(const half8f*)(F + ((8 + 2 * wc) << 9));
            half8f t1 = *(const half8f*)(F + ((9 + 2 * wc) << 9));
            accA[0][0] = MFMA(e0, q0, accA[0][0], 0, 0, 0);
            accA[0][1] = MFMA(e0, q1, accA[0][1], 0, 0, 0);
            accA[1][0] = MFMA(e1, q0, accA[1][0], 0, 0, 0);
            accA[1][1] = MFMA(e1, q1, accA[1][1], 0, 0, 0);
            accB[0][0] = MFMA(e0, t0, accB[0][0], 0, 0, 0);
            accB[0][1] = MFMA(e0, t1, accB[0][1], 0, 0, 0);
            accB[1][0] = MFMA(e1, t0, accB[1][0], 0, 0, 0);
            accB[1][1] = MFMA(e1, t1, accB[1][1], 0, 0, 0);
        }
        cur ^= 1;
    }
    const int dc = d0 + wc * 64 + (lane & 31);
#pragma unroll
    for (int i = 0; i < 2; ++i) {
#pragma unroll
        for (int r = 0; r < 16; ++r) {
            const int row = (r & 3) + ((r >> 2) << 3) + ((lane >> 5) << 2);
            const int n = n0 + wr * 64 + i * 32 + row;
            const float inv = __builtin_amdgcn_rcpf(rsum[b * NN + n]);
            const size_t o = ((size_t)(b * NN + n)) * DD + dc;
            outA[o]      = accA[i][0][r] * inv;
            outA[o + 32] = accA[i][1][r] * inv;
            outB[o]      = accB[i][0][r] * inv;
            outB[o + 32] = accB[i][1][r] * inv;
        }
    }
}

extern "C" void kernel_launch(void* const* d_in, const int* in_sizes, int n_in,
                              void* d_out, int out_size, void* d_ws, size_t ws_size,
                              hipStream_t stream) {
    const float* C = (const float*)d_in[0];
    const float* Q = (const float*)d_in[1];
    const int* Cmask = (const int*)d_in[2];
    const int* Qmask = (const int*)d_in[3];
    const float* w  = (const float*)d_in[4];

    const size_t BNM = (size_t)BB * NN * MM;   // 33.55M halves
    const size_t BMD = (size_t)BB * MM * DD;   // 8.39M halves
    const size_t BND = (size_t)BB * NN * DD;   // 33.55M halves
    const size_t BN  = (size_t)BB * NN;
    const size_t BM  = (size_t)BB * MM;

    // d_ws: E (packed), Tt (packed), PQt (packed) + fp32 vectors (~101 MB).
    _Float16* E   = (_Float16*)d_ws;
    _Float16* Tt  = E + BNM;
    _Float16* PQt = Tt + BMD;
    float* c1   = (float*)(PQt + BMD);
    float* q2   = c1 + BN;
    float* rsum = q2 + BM;
    float* csum = rsum + BN;

    // Scratch in d_out (268.4 MB): PCt | PCh | PQh | PEt = 67+67+16.8+67 = 218 MB.
    // PCh/PQh dead after k_sgemm; PCt/PEt dead after k_T;
    // k_AB then overwrites d_out with outA/outB.
    _Float16* PCt = (_Float16*)d_out;
    _Float16* PCh = PCt + BND;
    _Float16* PQh = PCh + BND;
    _Float16* PEt = PQh + BMD;

    hipMemsetAsync(c1, 0, 2 * (BN + BM) * sizeof(float), stream);  // c1,q2,rsum,csum contiguous

    k_prepQ<<<BB * 64, 256, 0, stream>>>(Q, Qmask, w, q2, PQt, PQh);
    k_prepC<<<BB * 256, 256, 0, stream>>>(C, w, c1, PCt, PCh);
    k_sgemm<<<2048, 256, 0, stream>>>(PCh, PQh, Cmask, Qmask, c1, q2, E, PEt, rsum, csum);
    k_T<<<512, 256, 0, stream>>>(PCt, PEt, csum, Qmask, Tt);
    k_AB<<<2048, 256, 0, stream>>>(E, PQt, Tt, rsum,
                                   (float*)d_out, (float*)d_out + BND);
}